// Round 12
// baseline (803.203 us; speedup 1.0000x reference)
//
#include <hip/hip_runtime.h>
#include <hip/hip_cooperative_groups.h>
#include <hip/hip_bf16.h>
#include <math.h>

// BinaryTreeLSTM — round 12: r11 + (a) LDS-staged coalesced GX C-write
// (kills 1.7x write amplification + RMW fetches), (b) cooperative tail
// kernel fusing levels k=7..0 with grid.sync (kills 8 dispatch drains,
// keeps Whh L2-resident).
//
// Packed gate-interleaved column space: e = (j/16)*64 + g*16 + (j%16)
//   (orig W row g*2048+j). Wih_p[4096][1024], Whh_p[4096][2048] bf16.
// GX[4096][4096] fp16: GX[node] = bf16(emb[node]) @ Wih_p^T + bge.
// Hcat: level-k h-slab at row OFF(k)=4096-2^(k+1), 2^k rows x 2048 bf16.
// c compact: level k writes even-node c at row m>>1 (1024 f32); k-1 reads row m.

#define TREE_DEPTH 12

namespace cg = cooperative_groups;

typedef unsigned short u16;
typedef unsigned int u32;
typedef __attribute__((ext_vector_type(8))) short bf16x8;
typedef __attribute__((ext_vector_type(4))) float f32x4;
typedef __attribute__((ext_vector_type(8))) unsigned short u16x8;
typedef __attribute__((ext_vector_type(2))) unsigned int u32x2;

__device__ __forceinline__ void gload16(const void* g, void* l) {
    __builtin_amdgcn_global_load_lds(
        (const __attribute__((address_space(1))) u32*)g,
        (__attribute__((address_space(3))) u32*)l, 16, 0, 0);
}

__device__ __forceinline__ u16 f2bf(float f) {
    __hip_bfloat16 h = __float2bfloat16(f);
    return *reinterpret_cast<u16*>(&h);
}
__device__ __forceinline__ u16 f2h(float f) {
    _Float16 h = (_Float16)f;
    return *reinterpret_cast<u16*>(&h);
}
__device__ __forceinline__ float h2f(u16 u) {
    _Float16 h;
    *reinterpret_cast<u16*>(&h) = u;
    return (float)h;
}

// ---------------------------------------------------------------- converts
__global__ void bias_e_kernel(const float* __restrict__ b_ih,
                              const float* __restrict__ b_hh,
                              float* __restrict__ bge) {
    int e = blockIdx.x * blockDim.x + threadIdx.x;   // 0..4095 packed order
    int g = (e >> 4) & 3;
    int j = (e >> 6) * 16 + (e & 15);
    int r = g * 2048 + j;
    bge[e] = b_ih[r] + b_hh[r];
}

__global__ void pack_w(const float* __restrict__ Wih,
                       const float* __restrict__ Whh,
                       u16* __restrict__ Wih_p, u16* __restrict__ Whh_p) {
    const int b = blockIdx.x;          // 0..4095
    const int seg = blockIdx.y;        // 0: ih, 1/2: hh halves
    const int x = b & 7, t = b >> 3;   // t in [0,512)
    const int e = ((t & 3) * 8 + x) * 128 + (t >> 2);  // (e>>7)%8 == x
    const int g = (e >> 4) & 3;
    const int j = (e >> 6) * 16 + (e & 15);
    const int wr = g * 2048 + j;
    const int col = threadIdx.x * 4;   // 0..1020
    f32x4 v;
    u16* dst;
    if (seg == 0) {
        v = __builtin_nontemporal_load(
            (const f32x4*)(Wih + (size_t)wr * 1024 + col));
        dst = Wih_p + (size_t)e * 1024 + col;
    } else {
        v = __builtin_nontemporal_load(
            (const f32x4*)(Whh + (size_t)wr * 2048 + (seg - 1) * 1024 + col));
        dst = Whh_p + (size_t)e * 2048 + (seg - 1) * 1024 + col;
    }
    u32x2 p;
    p[0] = (u32)f2bf(v[0]) | ((u32)f2bf(v[1]) << 16);
    p[1] = (u32)f2bf(v[2]) | ((u32)f2bf(v[3]) << 16);
    *reinterpret_cast<u32x2*>(dst) = p;
}

__global__ void conv_emb(const float* __restrict__ emb, u16* __restrict__ xb) {
    size_t idx = ((size_t)blockIdx.x * 256 + threadIdx.x) * 4;  // over 4095*1024
    f32x4 v = __builtin_nontemporal_load((const f32x4*)(emb + idx));
    u32x2 p;
    p[0] = (u32)f2bf(v[0]) | ((u32)f2bf(v[1]) << 16);
    p[1] = (u32)f2bf(v[2]) | ((u32)f2bf(v[3]) << 16);
    *reinterpret_cast<u32x2*>(xb + idx) = p;
}

// ---------------------------------------------------------------- GX GEMM
// GX[m][e] fp16 = xb[m] @ Wih_p[e] + bge[e].  M=4096, N=4096, K=1024.
// 128x128 tile, 4 waves, BK=32; C-tile staged in LDS -> coalesced 16B writes.
__global__ __launch_bounds__(256) void gemm_gx(
    const u16* __restrict__ xb, const u16* __restrict__ Wp,
    const float* __restrict__ bge, u16* __restrict__ GX)
{
    __shared__ u16 smem[16384];   // 32 KB: staging uses [0,8192), C-stage all

    const int gx_ = gridDim.x;   // 32
    int b = blockIdx.x + gx_ * blockIdx.y;
    const int x = b & 7, t = b >> 3;
    const int ct = (t & 3) * 8 + x;
    const int mt = t >> 2;
    const int m0 = mt * 128, c0 = ct * 128;

    const int tid = threadIdx.x, lane = tid & 63, w = tid >> 6;
    const int wr = (w >> 1) * 64, wc = (w & 1) * 64;

    f32x4 acc[4][4];
    #pragma unroll
    for (int i = 0; i < 4; ++i)
        #pragma unroll
        for (int j = 0; j < 4; ++j)
            acc[i][j] = f32x4{0.f, 0.f, 0.f, 0.f};

    const u16* gp[4];
    u16* dl[4];
    #pragma unroll
    for (int i = 0; i < 4; ++i) {
        const int s = tid + i * 256;
        const int row = s >> 2, kof = (s & 3) * 8;
        gp[i] = (row < 128) ? xb + (size_t)(m0 + row) * 1024 + kof
                            : Wp + (size_t)(c0 + row - 128) * 1024 + kof;
        dl[i] = smem + s * 8;
    }

    const int fl = lane & 15, kb = (lane >> 4) * 8;
    for (int k0 = 0; k0 < 1024; k0 += 32) {
        #pragma unroll
        for (int i = 0; i < 4; ++i) { gload16(gp[i], dl[i]); gp[i] += 32; }
        __syncthreads();
        bf16x8 a_[4], b_[4];
        #pragma unroll
        for (int i = 0; i < 4; ++i)
            a_[i] = *reinterpret_cast<const bf16x8*>(
                &smem[(wr + i * 16 + fl) * 32 + kb]);
        #pragma unroll
        for (int j = 0; j < 4; ++j)
            b_[j] = *reinterpret_cast<const bf16x8*>(
                &smem[(128 + wc + j * 16 + fl) * 32 + kb]);
        #pragma unroll
        for (int i = 0; i < 4; ++i)
            #pragma unroll
            for (int j = 0; j < 4; ++j)
                acc[i][j] = __builtin_amdgcn_mfma_f32_16x16x32_bf16(
                    a_[i], b_[j], acc[i][j], 0, 0, 0);
        __syncthreads();
    }

    // stage C (fp16 + bias) in LDS, then coalesced 16B-per-lane writes
    const int rg = (lane >> 4) * 4;
    #pragma unroll
    for (int i = 0; i < 4; ++i)
        #pragma unroll
        for (int j = 0; j < 4; ++j) {
            const float bv = bge[c0 + wc + j * 16 + fl];
            #pragma unroll
            for (int r = 0; r < 4; ++r)
                smem[(wr + i * 16 + rg + r) * 128 + (wc + j * 16 + fl)] =
                    f2h(acc[i][j][r] + bv);
        }
    __syncthreads();
    const int row_ = tid >> 4, chunk = tid & 15;
    #pragma unroll
    for (int it = 0; it < 8; ++it) {
        const int row = it * 16 + row_;
        u16x8 v = *reinterpret_cast<const u16x8*>(&smem[row * 128 + chunk * 8]);
        __builtin_nontemporal_store(
            v, (u16x8*)(GX + (size_t)(m0 + row) * 4096 + c0 + chunk * 8));
    }
}

// ---------------------------------------------------------------- level 11 act
__global__ void act_top(const u16* __restrict__ GX, u16* __restrict__ hdst,
                        float* __restrict__ cdst) {
    int idx = blockIdx.x * 256 + threadIdx.x;   // 0..262143
    int m = idx >> 7;            // 0..2047
    int jo = (idx & 127) * 8;    // 0..1016
    const u16* row = GX + (size_t)(2047 + m) * 4096;
    const int eb = (jo >> 4) * 64 + (jo & 8);
    u16x8 gi = __builtin_nontemporal_load((const u16x8*)(row + eb));
    u16x8 gg = __builtin_nontemporal_load((const u16x8*)(row + eb + 32));
    u16x8 go = __builtin_nontemporal_load((const u16x8*)(row + eb + 48));
    u16x8 hp;
    float cn[8];
    #pragma unroll
    for (int q = 0; q < 8; ++q) {
        const float i_ = h2f(gi[q]), g_ = h2f(gg[q]), o_ = h2f(go[q]);
        const float si = 1.0f / (1.0f + expf(-i_));
        const float so = 1.0f / (1.0f + expf(-o_));
        cn[q] = si * tanhf(g_);
        hp[q] = f2bf(so * tanhf(cn[q]));
    }
    *reinterpret_cast<u16x8*>(hdst + (size_t)(m >> 1) * 2048 +
                              (m & 1) * 1024 + jo) = hp;
    if (!(m & 1)) {
        f32x4 c0v = {cn[0], cn[1], cn[2], cn[3]};
        f32x4 c1v = {cn[4], cn[5], cn[6], cn[7]};
        float* cb = cdst + (size_t)(m >> 1) * 1024 + jo;
        __builtin_nontemporal_store(c0v, (f32x4*)cb);
        __builtin_nontemporal_store(c1v, (f32x4*)(cb + 4));
    }
}

// ---------------------------------------------------------------- fused level
// gates = A(h_cat) @ Whh_p^T + GX[node]; K=2048 split KG ways in-block.
template <int MI, int MW, int NW, int KG>
__global__ __launch_bounds__(MW* NW* KG * 64) void fused_level(
    const u16* __restrict__ A, const u16* __restrict__ Wp,
    const u16* __restrict__ GXl, const float* __restrict__ cprev,
    u16* __restrict__ hnext, float* __restrict__ cnext,
    float* __restrict__ outp, int n)
{
    constexpr int BM = MI * 16 * MW;
    constexpr int BN = NW * 64;
    constexpr int S = MW * NW;
    constexpr int NFR = MI * 4;
    constexpr int RC = NFR > 8 ? 8 : NFR;
    constexpr int NP = NFR / RC;
    constexpr int ROWS = BM + BN;
    constexpr int SLOTS = ROWS * 4;
    constexpr int GT = S * 64;
    constexpr int NL = SLOTS / GT;
    static_assert(SLOTS % GT == 0, "slot mapping must be exact");
    constexpr int STG = KG * ROWS * 64;
    constexpr int REDB = (KG > 1) ? (KG - 1) * S * RC * 64 * 16 : 0;
    constexpr int SMEM = STG > REDB ? STG : REDB;
    __shared__ __align__(16) char smem[SMEM];

    const int gx_ = gridDim.x;
    int b = blockIdx.x + gx_ * blockIdx.y;
    const int x = b & 7;
    int t = b >> 3;
    int ct, mt;
    if constexpr (NW == 2) {
        ct = (t & 3) * 8 + x; mt = t >> 2;
    } else {
        const int lo = t & 1; t >>= 1;
        ct = ((t & 3) * 8 + x) * 2 + lo; mt = t >> 2;
    }
    const int m0 = mt * BM;
    const int c0 = ct * BN;

    const int tid = threadIdx.x;
    const int lane = tid & 63;
    const int w = tid >> 6;
    const int kg = w / S;
    const int slot = w % S;
    const int wm = slot / NW;
    const int wn = slot % NW;

    const int Kc = 2048 / KG;
    const int kbeg = kg * Kc;

    u16* buf = (u16*)smem + (size_t)kg * ROWS * 32;

    const int gtid = slot * 64 + lane;
    const u16* gp[NL];
    u16* dl[NL];
    #pragma unroll
    for (int i = 0; i < NL; ++i) {
        const int s = gtid + i * GT;
        const int row = s >> 2;
        const int kof = (s & 3) * 8;
        if (row < BM) {
            int ar = m0 + row;
            if (ar >= n) ar = n - 1;
            gp[i] = A + (size_t)ar * 2048 + kbeg + kof;
        } else {
            gp[i] = Wp + (size_t)(c0 + row - BM) * 2048 + kbeg + kof;
        }
        dl[i] = buf + s * 8;
    }

    f32x4 acc[MI][4];
    #pragma unroll
    for (int mi = 0; mi < MI; ++mi)
        #pragma unroll
        for (int f = 0; f < 4; ++f)
            acc[mi][f] = f32x4{0.f, 0.f, 0.f, 0.f};

    const int fl = lane & 15;
    const int kb = (lane >> 4) * 8;
    const int ar0 = wm * MI * 16;
    const int bc0 = BM;

    for (int k0 = 0; k0 < Kc; k0 += 32) {
        #pragma unroll
        for (int i = 0; i < NL; ++i) { gload16(gp[i], dl[i]); gp[i] += 32; }
        __syncthreads();
        bf16x8 a_[MI], b_[4];
        #pragma unroll
        for (int mi = 0; mi < MI; ++mi)
            a_[mi] = *reinterpret_cast<const bf16x8*>(
                buf + (ar0 + mi * 16 + fl) * 32 + kb);
        #pragma unroll
        for (int f = 0; f < 4; ++f)
            b_[f] = *reinterpret_cast<const bf16x8*>(
                buf + (bc0 + wn * 64 + f * 16 + fl) * 32 + kb);
        #pragma unroll
        for (int mi = 0; mi < MI; ++mi)
            #pragma unroll
            for (int f = 0; f < 4; ++f)
                acc[mi][f] = __builtin_amdgcn_mfma_f32_16x16x32_bf16(
                    a_[mi], b_[f], acc[mi][f], 0, 0, 0);
        __syncthreads();
    }

    if constexpr (KG > 1) {
        f32x4* red = reinterpret_cast<f32x4*>(smem);
        #pragma unroll
        for (int pass = 0; pass < NP; ++pass) {
            if (kg > 0) {
                #pragma unroll
                for (int f = 0; f < RC; ++f) {
                    const int fr = pass * RC + f;
                    red[(((kg - 1) * S + slot) * RC + f) * 64 + lane] =
                        acc[fr >> 2][fr & 3];
                }
            }
            __syncthreads();
            if (kg == 0) {
                #pragma unroll
                for (int q = 1; q < KG; ++q)
                    #pragma unroll
                    for (int f = 0; f < RC; ++f) {
                        const int fr = pass * RC + f;
                        f32x4 v = red[(((q - 1) * S + slot) * RC + f) * 64 + lane];
                        acc[fr >> 2][fr & 3][0] += v[0];
                        acc[fr >> 2][fr & 3][1] += v[1];
                        acc[fr >> 2][fr & 3][2] += v[2];
                        acc[fr >> 2][fr & 3][3] += v[3];
                    }
            }
            __syncthreads();
        }
    }

    if (kg != 0) return;
    const int j = ((c0 + wn * 64) >> 6) * 16 + fl;
    #pragma unroll
    for (int mi = 0; mi < MI; ++mi) {
        #pragma unroll
        for (int r = 0; r < 4; ++r) {
            const int m = m0 + wm * MI * 16 + mi * 16 + (lane >> 4) * 4 + r;
            if (m >= n) continue;
            const u16* gx = GXl + (size_t)m * 4096 + c0 + wn * 64 + fl;
            const float i_ = acc[mi][0][r] + h2f(__builtin_nontemporal_load(gx));
            const float f_ = acc[mi][1][r] + h2f(__builtin_nontemporal_load(gx + 16));
            const float g_ = acc[mi][2][r] + h2f(__builtin_nontemporal_load(gx + 32));
            const float o_ = acc[mi][3][r] + h2f(__builtin_nontemporal_load(gx + 48));
            const float cc = __builtin_nontemporal_load(cprev + (size_t)m * 1024 + j);
            const float si = 1.0f / (1.0f + expf(-i_));
            const float sf = 1.0f / (1.0f + expf(-f_));
            const float so = 1.0f / (1.0f + expf(-o_));
            const float cn = sf * cc + si * tanhf(g_);
            const float hn = so * tanhf(cn);
            if (hnext)
                hnext[(size_t)(m >> 1) * 2048 + (m & 1) * 1024 + j] = f2bf(hn);
            if (!(m & 1))
                __builtin_nontemporal_store(cn, cnext + (size_t)(m >> 1) * 1024 + j);
            if (outp) { outp[j] = hn; outp[1024 + j] = cn; }
        }
    }
}

// ---------------------------------------------------------------- tail levels
// Cooperative kernel: levels k=7..0 with grid.sync between levels.
// 256 blocks x 8 waves; per task: 16x64 output tile, K=2048 split over 8 waves.
__global__ __launch_bounds__(512) void tail_levels(
    const u16* __restrict__ Wp, const u16* __restrict__ GX,
    u16* __restrict__ Hcat, float* cpv0, float* cnx0,
    float* __restrict__ out)
{
    constexpr int ROWS = 80;                       // 16 A + 64 B
    __shared__ __align__(16) char smem[8 * ROWS * 64];   // 40 KB (red needs 28)

    cg::grid_group grid = cg::this_grid();

    const int bid = blockIdx.x;        // 0..255
    const int tid = threadIdx.x;
    const int lane = tid & 63;
    const int kg = tid >> 6;           // 0..7
    const int fl = lane & 15;
    const int kb = (lane >> 4) * 8;
    const int kbeg = kg * 256;

    u16* buf = (u16*)smem + kg * ROWS * 32;
    f32x4* red = reinterpret_cast<f32x4*>(smem);

    float* cpv = cpv0;
    float* cnx = cnx0;

    for (int k = 7; k >= 0; --k) {
        const int n = 1 << k;
        const u16* A = Hcat + (size_t)(4096 - (2 << k)) * 2048;
        const u16* GXl = GX + (size_t)(n - 1) * 4096;
        u16* hnext = (k > 0) ? (Hcat + (size_t)(4096 - (1 << k)) * 2048) : nullptr;
        float* outp = (k == 0) ? out : nullptr;
        const int Mt = (n + 15) >> 4;
        const int ntask = Mt * 64;

        for (int task = bid; task < ntask; task += 256) {
            const int mt = task >> 6;
            const int ct = task & 63;
            const int m0 = mt * 16;
            const int c0 = ct * 64;

            const u16* gp[5];
            u16* dl[5];
            #pragma unroll
            for (int i = 0; i < 5; ++i) {
                const int s = lane + i * 64;       // 0..319
                const int row = s >> 2;
                const int kof = (s & 3) * 8;
                if (row < 16) {
                    int ar = m0 + row;
                    if (ar >= n) ar = n - 1;
                    gp[i] = A + (size_t)ar * 2048 + kbeg + kof;
                } else {
                    gp[i] = Wp + (size_t)(c0 + row - 16) * 2048 + kbeg + kof;
                }
                dl[i] = buf + s * 8;
            }

            f32x4 acc[4];
            #pragma unroll
            for (int f = 0; f < 4; ++f) acc[f] = f32x4{0.f, 0.f, 0.f, 0.f};

            for (int k0 = 0; k0 < 256; k0 += 32) {
                #pragma unroll
                for (int i = 0; i < 5; ++i) { gload16(gp[i], dl[i]); gp[i] += 32; }
                __syncthreads();
                bf16x8 a = *reinterpret_cast<const bf16x8*>(buf + fl * 32 + kb);
                #pragma unroll
                for (int f = 0; f < 4; ++f) {
                    bf16x8 bb = *reinterpret_cast<const bf16x8*>(
                        buf + (16 + f * 16 + fl) * 32 + kb);
                    acc[f] = __builtin_amdgcn_mfma_f32_16x16x32_bf16(
                        a, bb, acc[f], 0, 0, 0);
                }
                __syncthreads();
            }

            if (kg > 0) {
                #pragma unroll
                for (int f = 0; f < 4; ++f)
                    red[((kg - 1) * 4 + f) * 64 + lane] = acc[f];
            }
            __syncthreads();
            if (kg == 0) {
                #pragma unroll
                for (int q = 1; q < 8; ++q)
                    #pragma unroll
                    for (int f = 0; f < 4; ++f) {
                        f32x4 v = red[((q - 1) * 4 + f) * 64 + lane];
                        acc[f][0] += v[0]; acc[f][1] += v[1];
                        acc[f][2] += v[2]; acc[f][3] += v[3];
                    }
                const int j = ct * 16 + fl;
                #pragma unroll
                for (int r = 0; r < 4; ++r) {
                    const int m = m0 + (lane >> 4) * 4 + r;
                    if (m >= n) continue;
                    const u16* gx = GXl + (size_t)m * 4096 + c0 + fl;
                    const float i_ = acc[0][r] + h2f(gx[0]);
                    const float f_ = acc[1][r] + h2f(gx[16]);
                    const float g_ = acc[2][r] + h2f(gx[32]);
                    const float o_ = acc[3][r] + h2f(gx[48]);
                    const float cc = cpv[(size_t)m * 1024 + j];
                    const float si = 1.0f / (1.0f + expf(-i_));
                    const float sf = 1.0f / (1.0f + expf(-f_));
                    const float so = 1.0f / (1.0f + expf(-o_));
                    const float cn = sf * cc + si * tanhf(g_);
                    const float hn = so * tanhf(cn);
                    if (hnext)
                        hnext[(size_t)(m >> 1) * 2048 + (m & 1) * 1024 + j] = f2bf(hn);
                    if (!(m & 1))
                        cnx[(size_t)(m >> 1) * 1024 + j] = cn;
                    if (outp) { outp[j] = hn; outp[1024 + j] = cn; }
                }
            }
            __syncthreads();
        }
        __threadfence();
        grid.sync();
        float* tmp = cpv; cpv = cnx; cnx = tmp;
    }
}

// ---------------------------------------------------------------- launcher
extern "C" void kernel_launch(void* const* d_in, const int* in_sizes, int n_in,
                              void* d_out, int out_size, void* d_ws, size_t ws_size,
                              hipStream_t stream) {
    const float* emb  = (const float*)d_in[0];
    const float* W_ih = (const float*)d_in[1];
    const float* W_hh = (const float*)d_in[2];
    const float* b_ih = (const float*)d_in[3];
    const float* b_hh = (const float*)d_in[4];
    float* out = (float*)d_out;

    char* p = (char*)d_ws;
    float* bge  = (float*)p;  p += 16384;
    u16* Wih_p  = (u16*)p;    p += (size_t)4096 * 1024 * 2;   //  8.4 MB
    u16* Whh_p  = (u16*)p;    p += (size_t)4096 * 2048 * 2;   // 16.8 MB
    u16* xb     = (u16*)p;    p += (size_t)4096 * 1024 * 2;   //  8.4 MB
    u16* GX     = (u16*)p;    p += (size_t)4096 * 4096 * 2;   // 33.6 MB
    u16* Hcat   = (u16*)p;    p += (size_t)4096 * 2048 * 2;   // 16.8 MB
    float* cbA  = (float*)p;  p += (size_t)1024 * 1024 * 4;   //  4.2 MB
    float* cbB  = (float*)p;  p += (size_t)1024 * 1024 * 4;   //  4.2 MB

    bias_e_kernel<<<16, 256, 0, stream>>>(b_ih, b_hh, bge);
    pack_w<<<dim3(4096, 3), 256, 0, stream>>>(W_ih, W_hh, Wih_p, Whh_p);
    conv_emb<<<4095, 256, 0, stream>>>(emb, xb);

    gemm_gx<<<dim3(32, 32), 256, 0, stream>>>(xb, Wih_p, bge, GX);

    #define OFF(k) (4096 - (2 << (k)))

    act_top<<<1024, 256, 0, stream>>>(GX, Hcat + (size_t)OFF(10) * 2048, cbA);

    // k = 10, 9, 8 — measured fused path (r11).
    fused_level<4, 2, 2, 2><<<dim3(8, 32), 512, 0, stream>>>(
        Hcat + (size_t)OFF(10) * 2048, Whh_p, GX + (size_t)1023 * 4096,
        cbA, Hcat + (size_t)OFF(9) * 2048, cbB, nullptr, 1024);
    fused_level<4, 1, 2, 4><<<dim3(8, 32), 512, 0, stream>>>(
        Hcat + (size_t)OFF(9) * 2048, Whh_p, GX + (size_t)511 * 4096,
        cbB, Hcat + (size_t)OFF(8) * 2048, cbA, nullptr, 512);
    fused_level<2, 1, 2, 4><<<dim3(8, 32), 512, 0, stream>>>(
        Hcat + (size_t)OFF(8) * 2048, Whh_p, GX + (size_t)255 * 4096,
        cbA, Hcat + (size_t)OFF(7) * 2048, cbB, nullptr, 256);

    // k = 7..0 — one cooperative kernel, grid.sync between levels.
    {
        const u16* Wp_ = Whh_p;
        const u16* GX_ = GX;
        u16* H_ = Hcat;
        float* c0_ = cbB;    // cprev after k=8
        float* c1_ = cbA;
        float* out_ = out;
        void* args[] = {&Wp_, &GX_, &H_, &c0_, &c1_, &out_};
        hipLaunchCooperativeKernel(reinterpret_cast<void*>(tail_levels),
                                   dim3(256), dim3(512), args, 0, stream);
    }
}

// Round 13
// 292.141 us; speedup vs baseline: 2.7494x; 2.7494x over previous
//
#include <hip/hip_runtime.h>
#include <hip/hip_bf16.h>
#include <math.h>

// BinaryTreeLSTM — round 13: r11 structure (best-known 300us) + LDS-staged
// coalesced GX C-write (r12's one good idea; bank-padded stride 140).
// Cooperative tail REVERTED: grid.sync measured ~74us/sync on gfx950 (r12);
// per-level dispatches with stable XCD<->weight-tile affinity give L2-resident
// weights (r12 counter evidence: 14.6MB FETCH for 8 levels) at ~2-4us/dispatch.
//
// Packed gate-interleaved column space: e = (j/16)*64 + g*16 + (j%16)
//   (orig W row g*2048+j). Wih_p[4096][1024], Whh_p[4096][2048] bf16,
//   XCD-affine 128-row tiles: tile (e>>7) written by blocks with b&7==(e>>7)%8.
// GX[4096][4096] fp16: GX[node] = bf16(emb[node]) @ Wih_p^T + bge.
// Hcat: level-k h-slab at row OFF(k)=4096-2^(k+1), 2^k rows x 2048 bf16.
// c compact: level k writes even-node c at row m>>1 (1024 f32); k-1 reads row m.

#define TREE_DEPTH 12

typedef unsigned short u16;
typedef unsigned int u32;
typedef __attribute__((ext_vector_type(8))) short bf16x8;
typedef __attribute__((ext_vector_type(4))) float f32x4;
typedef __attribute__((ext_vector_type(8))) unsigned short u16x8;
typedef __attribute__((ext_vector_type(2))) unsigned int u32x2;

__device__ __forceinline__ void gload16(const void* g, void* l) {
    __builtin_amdgcn_global_load_lds(
        (const __attribute__((address_space(1))) u32*)g,
        (__attribute__((address_space(3))) u32*)l, 16, 0, 0);
}

__device__ __forceinline__ u16 f2bf(float f) {
    __hip_bfloat16 h = __float2bfloat16(f);
    return *reinterpret_cast<u16*>(&h);
}
__device__ __forceinline__ u16 f2h(float f) {
    _Float16 h = (_Float16)f;
    return *reinterpret_cast<u16*>(&h);
}
__device__ __forceinline__ float h2f(u16 u) {
    _Float16 h;
    *reinterpret_cast<u16*>(&h) = u;
    return (float)h;
}

// ---------------------------------------------------------------- converts
__global__ void bias_e_kernel(const float* __restrict__ b_ih,
                              const float* __restrict__ b_hh,
                              float* __restrict__ bge) {
    int e = blockIdx.x * blockDim.x + threadIdx.x;   // 0..4095 packed order
    int g = (e >> 4) & 3;
    int j = (e >> 6) * 16 + (e & 15);
    int r = g * 2048 + j;
    bge[e] = b_ih[r] + b_hh[r];
}

__global__ void pack_w(const float* __restrict__ Wih,
                       const float* __restrict__ Whh,
                       u16* __restrict__ Wih_p, u16* __restrict__ Whh_p) {
    const int b = blockIdx.x;          // 0..4095
    const int seg = blockIdx.y;        // 0: ih, 1/2: hh halves
    const int x = b & 7, t = b >> 3;   // t in [0,512)
    const int e = ((t & 3) * 8 + x) * 128 + (t >> 2);  // (e>>7)%8 == x
    const int g = (e >> 4) & 3;
    const int j = (e >> 6) * 16 + (e & 15);
    const int wr = g * 2048 + j;
    const int col = threadIdx.x * 4;   // 0..1020
    f32x4 v;
    u16* dst;
    if (seg == 0) {
        v = __builtin_nontemporal_load(
            (const f32x4*)(Wih + (size_t)wr * 1024 + col));
        dst = Wih_p + (size_t)e * 1024 + col;
    } else {
        v = __builtin_nontemporal_load(
            (const f32x4*)(Whh + (size_t)wr * 2048 + (seg - 1) * 1024 + col));
        dst = Whh_p + (size_t)e * 2048 + (seg - 1) * 1024 + col;
    }
    u32x2 p;
    p[0] = (u32)f2bf(v[0]) | ((u32)f2bf(v[1]) << 16);
    p[1] = (u32)f2bf(v[2]) | ((u32)f2bf(v[3]) << 16);
    *reinterpret_cast<u32x2*>(dst) = p;
}

__global__ void conv_emb(const float* __restrict__ emb, u16* __restrict__ xb) {
    size_t idx = ((size_t)blockIdx.x * 256 + threadIdx.x) * 4;  // over 4095*1024
    f32x4 v = __builtin_nontemporal_load((const f32x4*)(emb + idx));
    u32x2 p;
    p[0] = (u32)f2bf(v[0]) | ((u32)f2bf(v[1]) << 16);
    p[1] = (u32)f2bf(v[2]) | ((u32)f2bf(v[3]) << 16);
    *reinterpret_cast<u32x2*>(xb + idx) = p;
}

// ---------------------------------------------------------------- GX GEMM
// GX[m][e] fp16 = xb[m] @ Wih_p[e] + bge[e].  M=4096, N=4096, K=1024.
// 128x128 tile, 4 waves, BK=32; C staged in LDS (stride 140 u16: write-phase
// lane groups hit disjoint bank windows) -> coalesced 16B/lane stores.
__global__ __launch_bounds__(256) void gemm_gx(
    const u16* __restrict__ xb, const u16* __restrict__ Wp,
    const float* __restrict__ bge, u16* __restrict__ GX)
{
    __shared__ u16 smem[128 * 140];   // 35 KB; staging uses [0,8192)

    const int gx_ = gridDim.x;   // 32
    int b = blockIdx.x + gx_ * blockIdx.y;
    const int x = b & 7, t = b >> 3;
    const int ct = (t & 3) * 8 + x;
    const int mt = t >> 2;
    const int m0 = mt * 128, c0 = ct * 128;

    const int tid = threadIdx.x, lane = tid & 63, w = tid >> 6;
    const int wr = (w >> 1) * 64, wc = (w & 1) * 64;

    f32x4 acc[4][4];
    #pragma unroll
    for (int i = 0; i < 4; ++i)
        #pragma unroll
        for (int j = 0; j < 4; ++j)
            acc[i][j] = f32x4{0.f, 0.f, 0.f, 0.f};

    const u16* gp[4];
    u16* dl[4];
    #pragma unroll
    for (int i = 0; i < 4; ++i) {
        const int s = tid + i * 256;
        const int row = s >> 2, kof = (s & 3) * 8;
        gp[i] = (row < 128) ? xb + (size_t)(m0 + row) * 1024 + kof
                            : Wp + (size_t)(c0 + row - 128) * 1024 + kof;
        dl[i] = smem + s * 8;
    }

    const int fl = lane & 15, kb = (lane >> 4) * 8;
    for (int k0 = 0; k0 < 1024; k0 += 32) {
        #pragma unroll
        for (int i = 0; i < 4; ++i) { gload16(gp[i], dl[i]); gp[i] += 32; }
        __syncthreads();
        bf16x8 a_[4], b_[4];
        #pragma unroll
        for (int i = 0; i < 4; ++i)
            a_[i] = *reinterpret_cast<const bf16x8*>(
                &smem[(wr + i * 16 + fl) * 32 + kb]);
        #pragma unroll
        for (int j = 0; j < 4; ++j)
            b_[j] = *reinterpret_cast<const bf16x8*>(
                &smem[(128 + wc + j * 16 + fl) * 32 + kb]);
        #pragma unroll
        for (int i = 0; i < 4; ++i)
            #pragma unroll
            for (int j = 0; j < 4; ++j)
                acc[i][j] = __builtin_amdgcn_mfma_f32_16x16x32_bf16(
                    a_[i], b_[j], acc[i][j], 0, 0, 0);
        __syncthreads();
    }

    // stage C (fp16 + bias) in LDS, then coalesced 16B-per-lane writes
    const int rg = (lane >> 4) * 4;
    #pragma unroll
    for (int i = 0; i < 4; ++i)
        #pragma unroll
        for (int j = 0; j < 4; ++j) {
            const float bv = bge[c0 + wc + j * 16 + fl];
            #pragma unroll
            for (int r = 0; r < 4; ++r)
                smem[(wr + i * 16 + rg + r) * 140 + (wc + j * 16 + fl)] =
                    f2h(acc[i][j][r] + bv);
        }
    __syncthreads();
    const int row_ = tid >> 4, chunk = tid & 15;
    #pragma unroll
    for (int it = 0; it < 8; ++it) {
        const int row = it * 16 + row_;
        u16x8 v = *reinterpret_cast<const u16x8*>(&smem[row * 140 + chunk * 8]);
        __builtin_nontemporal_store(
            v, (u16x8*)(GX + (size_t)(m0 + row) * 4096 + c0 + chunk * 8));
    }
}

// ---------------------------------------------------------------- level 11 act
__global__ void act_top(const u16* __restrict__ GX, u16* __restrict__ hdst,
                        float* __restrict__ cdst) {
    int idx = blockIdx.x * 256 + threadIdx.x;   // 0..262143
    int m = idx >> 7;            // 0..2047
    int jo = (idx & 127) * 8;    // 0..1016
    const u16* row = GX + (size_t)(2047 + m) * 4096;
    const int eb = (jo >> 4) * 64 + (jo & 8);
    u16x8 gi = __builtin_nontemporal_load((const u16x8*)(row + eb));
    u16x8 gg = __builtin_nontemporal_load((const u16x8*)(row + eb + 32));
    u16x8 go = __builtin_nontemporal_load((const u16x8*)(row + eb + 48));
    u16x8 hp;
    float cn[8];
    #pragma unroll
    for (int q = 0; q < 8; ++q) {
        const float i_ = h2f(gi[q]), g_ = h2f(gg[q]), o_ = h2f(go[q]);
        const float si = 1.0f / (1.0f + expf(-i_));
        const float so = 1.0f / (1.0f + expf(-o_));
        cn[q] = si * tanhf(g_);
        hp[q] = f2bf(so * tanhf(cn[q]));
    }
    *reinterpret_cast<u16x8*>(hdst + (size_t)(m >> 1) * 2048 +
                              (m & 1) * 1024 + jo) = hp;
    if (!(m & 1)) {
        f32x4 c0v = {cn[0], cn[1], cn[2], cn[3]};
        f32x4 c1v = {cn[4], cn[5], cn[6], cn[7]};
        float* cb = cdst + (size_t)(m >> 1) * 1024 + jo;
        __builtin_nontemporal_store(c0v, (f32x4*)cb);
        __builtin_nontemporal_store(c1v, (f32x4*)(cb + 4));
    }
}

// ---------------------------------------------------------------- fused level
// gates = A(h_cat) @ Whh_p^T + GX[node]; K=2048 split KG ways in-block.
template <int MI, int MW, int NW, int KG>
__global__ __launch_bounds__(MW* NW* KG * 64) void fused_level(
    const u16* __restrict__ A, const u16* __restrict__ Wp,
    const u16* __restrict__ GXl, const float* __restrict__ cprev,
    u16* __restrict__ hnext, float* __restrict__ cnext,
    float* __restrict__ outp, int n)
{
    constexpr int BM = MI * 16 * MW;
    constexpr int BN = NW * 64;
    constexpr int S = MW * NW;
    constexpr int NFR = MI * 4;
    constexpr int RC = NFR > 8 ? 8 : NFR;
    constexpr int NP = NFR / RC;
    constexpr int ROWS = BM + BN;
    constexpr int SLOTS = ROWS * 4;
    constexpr int GT = S * 64;
    constexpr int NL = SLOTS / GT;
    static_assert(SLOTS % GT == 0, "slot mapping must be exact");
    constexpr int STG = KG * ROWS * 64;
    constexpr int REDB = (KG > 1) ? (KG - 1) * S * RC * 64 * 16 : 0;
    constexpr int SMEM = STG > REDB ? STG : REDB;
    __shared__ __align__(16) char smem[SMEM];

    const int gx_ = gridDim.x;
    int b = blockIdx.x + gx_ * blockIdx.y;
    const int x = b & 7;
    int t = b >> 3;
    int ct, mt;
    if constexpr (NW == 2) {
        ct = (t & 3) * 8 + x; mt = t >> 2;
    } else {
        const int lo = t & 1; t >>= 1;
        ct = ((t & 3) * 8 + x) * 2 + lo; mt = t >> 2;
    }
    const int m0 = mt * BM;
    const int c0 = ct * BN;

    const int tid = threadIdx.x;
    const int lane = tid & 63;
    const int w = tid >> 6;
    const int kg = w / S;
    const int slot = w % S;
    const int wm = slot / NW;
    const int wn = slot % NW;

    const int Kc = 2048 / KG;
    const int kbeg = kg * Kc;

    u16* buf = (u16*)smem + (size_t)kg * ROWS * 32;

    const int gtid = slot * 64 + lane;
    const u16* gp[NL];
    u16* dl[NL];
    #pragma unroll
    for (int i = 0; i < NL; ++i) {
        const int s = gtid + i * GT;
        const int row = s >> 2;
        const int kof = (s & 3) * 8;
        if (row < BM) {
            int ar = m0 + row;
            if (ar >= n) ar = n - 1;
            gp[i] = A + (size_t)ar * 2048 + kbeg + kof;
        } else {
            gp[i] = Wp + (size_t)(c0 + row - BM) * 2048 + kbeg + kof;
        }
        dl[i] = buf + s * 8;
    }

    f32x4 acc[MI][4];
    #pragma unroll
    for (int mi = 0; mi < MI; ++mi)
        #pragma unroll
        for (int f = 0; f < 4; ++f)
            acc[mi][f] = f32x4{0.f, 0.f, 0.f, 0.f};

    const int fl = lane & 15;
    const int kb = (lane >> 4) * 8;
    const int ar0 = wm * MI * 16;
    const int bc0 = BM;

    for (int k0 = 0; k0 < Kc; k0 += 32) {
        #pragma unroll
        for (int i = 0; i < NL; ++i) { gload16(gp[i], dl[i]); gp[i] += 32; }
        __syncthreads();
        bf16x8 a_[MI], b_[4];
        #pragma unroll
        for (int mi = 0; mi < MI; ++mi)
            a_[mi] = *reinterpret_cast<const bf16x8*>(
                buf + (ar0 + mi * 16 + fl) * 32 + kb);
        #pragma unroll
        for (int f = 0; f < 4; ++f)
            b_[f] = *reinterpret_cast<const bf16x8*>(
                buf + (bc0 + wn * 64 + f * 16 + fl) * 32 + kb);
        #pragma unroll
        for (int mi = 0; mi < MI; ++mi)
            #pragma unroll
            for (int f = 0; f < 4; ++f)
                acc[mi][f] = __builtin_amdgcn_mfma_f32_16x16x32_bf16(
                    a_[mi], b_[f], acc[mi][f], 0, 0, 0);
        __syncthreads();
    }

    if constexpr (KG > 1) {
        f32x4* red = reinterpret_cast<f32x4*>(smem);
        #pragma unroll
        for (int pass = 0; pass < NP; ++pass) {
            if (kg > 0) {
                #pragma unroll
                for (int f = 0; f < RC; ++f) {
                    const int fr = pass * RC + f;
                    red[(((kg - 1) * S + slot) * RC + f) * 64 + lane] =
                        acc[fr >> 2][fr & 3];
                }
            }
            __syncthreads();
            if (kg == 0) {
                #pragma unroll
                for (int q = 1; q < KG; ++q)
                    #pragma unroll
                    for (int f = 0; f < RC; ++f) {
                        const int fr = pass * RC + f;
                        f32x4 v = red[(((q - 1) * S + slot) * RC + f) * 64 + lane];
                        acc[fr >> 2][fr & 3][0] += v[0];
                        acc[fr >> 2][fr & 3][1] += v[1];
                        acc[fr >> 2][fr & 3][2] += v[2];
                        acc[fr >> 2][fr & 3][3] += v[3];
                    }
            }
            __syncthreads();
        }
    }

    if (kg != 0) return;
    const int j = ((c0 + wn * 64) >> 6) * 16 + fl;
    #pragma unroll
    for (int mi = 0; mi < MI; ++mi) {
        #pragma unroll
        for (int r = 0; r < 4; ++r) {
            const int m = m0 + wm * MI * 16 + mi * 16 + (lane >> 4) * 4 + r;
            if (m >= n) continue;
            const u16* gx = GXl + (size_t)m * 4096 + c0 + wn * 64 + fl;
            const float i_ = acc[mi][0][r] + h2f(__builtin_nontemporal_load(gx));
            const float f_ = acc[mi][1][r] + h2f(__builtin_nontemporal_load(gx + 16));
            const float g_ = acc[mi][2][r] + h2f(__builtin_nontemporal_load(gx + 32));
            const float o_ = acc[mi][3][r] + h2f(__builtin_nontemporal_load(gx + 48));
            const float cc = __builtin_nontemporal_load(cprev + (size_t)m * 1024 + j);
            const float si = 1.0f / (1.0f + expf(-i_));
            const float sf = 1.0f / (1.0f + expf(-f_));
            const float so = 1.0f / (1.0f + expf(-o_));
            const float cn = sf * cc + si * tanhf(g_);
            const float hn = so * tanhf(cn);
            if (hnext)
                hnext[(size_t)(m >> 1) * 2048 + (m & 1) * 1024 + j] = f2bf(hn);
            if (!(m & 1))
                __builtin_nontemporal_store(cn, cnext + (size_t)(m >> 1) * 1024 + j);
            if (outp) { outp[j] = hn; outp[1024 + j] = cn; }
        }
    }
}

// ---------------------------------------------------------------- launcher
extern "C" void kernel_launch(void* const* d_in, const int* in_sizes, int n_in,
                              void* d_out, int out_size, void* d_ws, size_t ws_size,
                              hipStream_t stream) {
    const float* emb  = (const float*)d_in[0];
    const float* W_ih = (const float*)d_in[1];
    const float* W_hh = (const float*)d_in[2];
    const float* b_ih = (const float*)d_in[3];
    const float* b_hh = (const float*)d_in[4];
    float* out = (float*)d_out;

    char* p = (char*)d_ws;
    float* bge  = (float*)p;  p += 16384;
    u16* Wih_p  = (u16*)p;    p += (size_t)4096 * 1024 * 2;   //  8.4 MB
    u16* Whh_p  = (u16*)p;    p += (size_t)4096 * 2048 * 2;   // 16.8 MB
    u16* xb     = (u16*)p;    p += (size_t)4096 * 1024 * 2;   //  8.4 MB
    u16* GX     = (u16*)p;    p += (size_t)4096 * 4096 * 2;   // 33.6 MB
    u16* Hcat   = (u16*)p;    p += (size_t)4096 * 2048 * 2;   // 16.8 MB
    float* cbA  = (float*)p;  p += (size_t)1024 * 1024 * 4;   //  4.2 MB
    float* cbB  = (float*)p;  p += (size_t)1024 * 1024 * 4;   //  4.2 MB

    bias_e_kernel<<<16, 256, 0, stream>>>(b_ih, b_hh, bge);
    pack_w<<<dim3(4096, 3), 256, 0, stream>>>(W_ih, W_hh, Wih_p, Whh_p);
    conv_emb<<<4095, 256, 0, stream>>>(emb, xb);

    // GX for all nodes: 1024 blocks of 128x128 (4/CU).
    gemm_gx<<<dim3(32, 32), 256, 0, stream>>>(xb, Wih_p, bge, GX);

    #define OFF(k) (4096 - (2 << (k)))

    // level 11 is pure act from GX.
    act_top<<<1024, 256, 0, stream>>>(GX, Hcat + (size_t)OFF(10) * 2048, cbA);

    const float* cprev = cbA;
    float* cbufs[2] = {cbB, cbA};
    int t = 0;
    for (int k = TREE_DEPTH - 2; k >= 0; --k) {
        const int n = 1 << k;
        const u16* A = Hcat + (size_t)OFF(k) * 2048;
        const u16* GXl = GX + (size_t)(n - 1) * 4096;
        u16* hnext = (k > 0) ? (Hcat + (size_t)OFF(k - 1) * 2048) : nullptr;
        float* cnext = cbufs[t];
        float* outp = (k == 0) ? out : nullptr;

        if (k == 10) {
            // BM=128, BN=128, 8 waves (4 compute x KG=2): 256 blocks.
            fused_level<4, 2, 2, 2><<<dim3(8, 32), 512, 0, stream>>>(
                A, Whh_p, GXl, cprev, hnext, cnext, outp, n);
        } else if (k == 9) {
            // BM=64, BN=128, 8 waves (2 x KG=4): 256 blocks.
            fused_level<4, 1, 2, 4><<<dim3(8, 32), 512, 0, stream>>>(
                A, Whh_p, GXl, cprev, hnext, cnext, outp, n);
        } else if (k == 8) {
            // BM=32, BN=128, 8 waves (2 x KG=4): 256 blocks.
            fused_level<2, 1, 2, 4><<<dim3(8, 32), 512, 0, stream>>>(
                A, Whh_p, GXl, cprev, hnext, cnext, outp, n);
        } else {
            // BM=16, BN=64, 8 waves (1 x KG=8): up to 512 blocks.
            const int gx = (n >= 16) ? n / 16 : 1;
            fused_level<1, 1, 1, 8><<<dim3(gx, 64), 512, 0, stream>>>(
                A, Whh_p, GXl, cprev, hnext, cnext, outp, n);
        }
        cprev = cnext; t ^= 1;
    }
}

// Round 14
// 287.075 us; speedup vs baseline: 2.7979x; 1.0176x over previous
//
#include <hip/hip_runtime.h>
#include <hip/hip_bf16.h>
#include <math.h>

// BinaryTreeLSTM — round 14: r13 + (a) level-11 LSTM cell fused into the
// gemm_gx epilogue (GX rows >= 2047 never materialized; act_top removed),
// (b) mid-level occupancy geometry: 256-thr blocks at 2-4 blocks/CU
// (L10 <4,1,2,2> 512 blk, L9 <2,1,2,2> 512 blk, L8 <1,1,1,4> 1024 blk)
// so independent blocks overlap staging stalls (m114 mechanism).
//
// Packed gate-interleaved column space: e = (j/16)*64 + g*16 + (j%16)
//   (orig W row g*2048+j). Wih_p[4096][1024], Whh_p[4096][2048] bf16,
//   XCD-affine 128-row tiles: tile (e>>7) written by blocks with b&7==(e>>7)%8.
// GX[4096][4096] fp16: rows 0..2046 only = bf16(emb[node]) @ Wih_p^T + bge.
// Hcat: level-k h-slab at row OFF(k)=4096-2^(k+1), 2^k rows x 2048 bf16.
// c compact: level k writes even-node c at row m>>1 (1024 f32); k-1 reads row m.

#define TREE_DEPTH 12

typedef unsigned short u16;
typedef unsigned int u32;
typedef __attribute__((ext_vector_type(8))) short bf16x8;
typedef __attribute__((ext_vector_type(4))) float f32x4;
typedef __attribute__((ext_vector_type(8))) unsigned short u16x8;
typedef __attribute__((ext_vector_type(2))) unsigned int u32x2;

__device__ __forceinline__ void gload16(const void* g, void* l) {
    __builtin_amdgcn_global_load_lds(
        (const __attribute__((address_space(1))) u32*)g,
        (__attribute__((address_space(3))) u32*)l, 16, 0, 0);
}

__device__ __forceinline__ u16 f2bf(float f) {
    __hip_bfloat16 h = __float2bfloat16(f);
    return *reinterpret_cast<u16*>(&h);
}
__device__ __forceinline__ u16 f2h(float f) {
    _Float16 h = (_Float16)f;
    return *reinterpret_cast<u16*>(&h);
}
__device__ __forceinline__ float h2f(u16 u) {
    _Float16 h;
    *reinterpret_cast<u16*>(&h) = u;
    return (float)h;
}

// ---------------------------------------------------------------- converts
__global__ void bias_e_kernel(const float* __restrict__ b_ih,
                              const float* __restrict__ b_hh,
                              float* __restrict__ bge) {
    int e = blockIdx.x * blockDim.x + threadIdx.x;   // 0..4095 packed order
    int g = (e >> 4) & 3;
    int j = (e >> 6) * 16 + (e & 15);
    int r = g * 2048 + j;
    bge[e] = b_ih[r] + b_hh[r];
}

__global__ void pack_w(const float* __restrict__ Wih,
                       const float* __restrict__ Whh,
                       u16* __restrict__ Wih_p, u16* __restrict__ Whh_p) {
    const int b = blockIdx.x;          // 0..4095
    const int seg = blockIdx.y;        // 0: ih, 1/2: hh halves
    const int x = b & 7, t = b >> 3;   // t in [0,512)
    const int e = ((t & 3) * 8 + x) * 128 + (t >> 2);  // (e>>7)%8 == x
    const int g = (e >> 4) & 3;
    const int j = (e >> 6) * 16 + (e & 15);
    const int wr = g * 2048 + j;
    const int col = threadIdx.x * 4;   // 0..1020
    f32x4 v;
    u16* dst;
    if (seg == 0) {
        v = __builtin_nontemporal_load(
            (const f32x4*)(Wih + (size_t)wr * 1024 + col));
        dst = Wih_p + (size_t)e * 1024 + col;
    } else {
        v = __builtin_nontemporal_load(
            (const f32x4*)(Whh + (size_t)wr * 2048 + (seg - 1) * 1024 + col));
        dst = Whh_p + (size_t)e * 2048 + (seg - 1) * 1024 + col;
    }
    u32x2 p;
    p[0] = (u32)f2bf(v[0]) | ((u32)f2bf(v[1]) << 16);
    p[1] = (u32)f2bf(v[2]) | ((u32)f2bf(v[3]) << 16);
    *reinterpret_cast<u32x2*>(dst) = p;
}

__global__ void conv_emb(const float* __restrict__ emb, u16* __restrict__ xb) {
    size_t idx = ((size_t)blockIdx.x * 256 + threadIdx.x) * 4;  // over 4095*1024
    f32x4 v = __builtin_nontemporal_load((const f32x4*)(emb + idx));
    u32x2 p;
    p[0] = (u32)f2bf(v[0]) | ((u32)f2bf(v[1]) << 16);
    p[1] = (u32)f2bf(v[2]) | ((u32)f2bf(v[3]) << 16);
    *reinterpret_cast<u32x2*>(xb + idx) = p;
}

// ---------------------------------------------------------------- GX GEMM
// Rows < 2047: GX[m][e] fp16 = xb[m] @ Wih_p[e] + bge[e] (LDS-staged store).
// Rows >= 2047 (level-11 nodes): LSTM cell in-register (c=0), h -> Hcat L10
// slab, even-node c -> cdst.  M=4096, N=4096, K=1024; 128x128 tile, 4 waves.
__global__ __launch_bounds__(256) void gemm_gx(
    const u16* __restrict__ xb, const u16* __restrict__ Wp,
    const float* __restrict__ bge, u16* __restrict__ GX,
    u16* __restrict__ hdst, float* __restrict__ cdst)
{
    __shared__ u16 smem[128 * 140];   // 35 KB; staging uses [0,8192)

    const int gx_ = gridDim.x;   // 32
    int b = blockIdx.x + gx_ * blockIdx.y;
    const int x = b & 7, t = b >> 3;
    const int ct = (t & 3) * 8 + x;
    const int mt = t >> 2;
    const int m0 = mt * 128, c0 = ct * 128;

    const int tid = threadIdx.x, lane = tid & 63, w = tid >> 6;
    const int wr = (w >> 1) * 64, wc = (w & 1) * 64;

    f32x4 acc[4][4];
    #pragma unroll
    for (int i = 0; i < 4; ++i)
        #pragma unroll
        for (int j = 0; j < 4; ++j)
            acc[i][j] = f32x4{0.f, 0.f, 0.f, 0.f};

    const u16* gp[4];
    u16* dl[4];
    #pragma unroll
    for (int i = 0; i < 4; ++i) {
        const int s = tid + i * 256;
        const int row = s >> 2, kof = (s & 3) * 8;
        gp[i] = (row < 128) ? xb + (size_t)(m0 + row) * 1024 + kof
                            : Wp + (size_t)(c0 + row - 128) * 1024 + kof;
        dl[i] = smem + s * 8;
    }

    const int fl = lane & 15, kb = (lane >> 4) * 8;
    for (int k0 = 0; k0 < 1024; k0 += 32) {
        #pragma unroll
        for (int i = 0; i < 4; ++i) { gload16(gp[i], dl[i]); gp[i] += 32; }
        __syncthreads();
        bf16x8 a_[4], b_[4];
        #pragma unroll
        for (int i = 0; i < 4; ++i)
            a_[i] = *reinterpret_cast<const bf16x8*>(
                &smem[(wr + i * 16 + fl) * 32 + kb]);
        #pragma unroll
        for (int j = 0; j < 4; ++j)
            b_[j] = *reinterpret_cast<const bf16x8*>(
                &smem[(128 + wc + j * 16 + fl) * 32 + kb]);
        #pragma unroll
        for (int i = 0; i < 4; ++i)
            #pragma unroll
            for (int j = 0; j < 4; ++j)
                acc[i][j] = __builtin_amdgcn_mfma_f32_16x16x32_bf16(
                    a_[i], b_[j], acc[i][j], 0, 0, 0);
        __syncthreads();
    }

    const int rg = (lane >> 4) * 4;
    if (m0 < 2047) {
        // stage C (fp16 + bias) in LDS (stride 140), coalesced 16B stores
        #pragma unroll
        for (int i = 0; i < 4; ++i)
            #pragma unroll
            for (int j = 0; j < 4; ++j) {
                const float bv = bge[c0 + wc + j * 16 + fl];
                #pragma unroll
                for (int r = 0; r < 4; ++r)
                    smem[(wr + i * 16 + rg + r) * 140 + (wc + j * 16 + fl)] =
                        f2h(acc[i][j][r] + bv);
            }
        __syncthreads();
        const int row_ = tid >> 4, chunk = tid & 15;
        #pragma unroll
        for (int it = 0; it < 8; ++it) {
            const int row = it * 16 + row_;
            if (m0 + row < 2047) {
                u16x8 v = *reinterpret_cast<const u16x8*>(
                    &smem[row * 140 + chunk * 8]);
                __builtin_nontemporal_store(
                    v, (u16x8*)(GX + (size_t)(m0 + row) * 4096 + c0 + chunk * 8));
            }
        }
    }
    if (m0 + 127 >= 2047) {
        // level-11 LSTM cell: c_prev = 0, f-gate unused.
        const int jj = ((c0 + wc) >> 6) * 16 + fl;
        const float bi  = bge[c0 + wc + fl];
        const float bgg = bge[c0 + wc + 32 + fl];
        const float bo  = bge[c0 + wc + 48 + fl];
        #pragma unroll
        for (int i = 0; i < 4; ++i) {
            #pragma unroll
            for (int r = 0; r < 4; ++r) {
                const int m = m0 + wr + i * 16 + rg + r;
                if (m < 2047 || m >= 4095) continue;
                const int mm = m - 2047;
                const float i_ = acc[i][0][r] + bi;
                const float g_ = acc[i][2][r] + bgg;
                const float o_ = acc[i][3][r] + bo;
                const float si = 1.0f / (1.0f + expf(-i_));
                const float so = 1.0f / (1.0f + expf(-o_));
                const float cn = si * tanhf(g_);
                const float hn = so * tanhf(cn);
                hdst[(size_t)(mm >> 1) * 2048 + (mm & 1) * 1024 + jj] = f2bf(hn);
                if (!(mm & 1))
                    cdst[(size_t)(mm >> 1) * 1024 + jj] = cn;
            }
        }
    }
}

// ---------------------------------------------------------------- fused level
// gates = A(h_cat) @ Whh_p^T + GX[node]; K=2048 split KG ways in-block.
template <int MI, int MW, int NW, int KG>
__global__ __launch_bounds__(MW* NW* KG * 64) void fused_level(
    const u16* __restrict__ A, const u16* __restrict__ Wp,
    const u16* __restrict__ GXl, const float* __restrict__ cprev,
    u16* __restrict__ hnext, float* __restrict__ cnext,
    float* __restrict__ outp, int n)
{
    constexpr int BM = MI * 16 * MW;
    constexpr int BN = NW * 64;
    constexpr int S = MW * NW;
    constexpr int NFR = MI * 4;
    constexpr int RC = NFR > 8 ? 8 : NFR;
    constexpr int NP = NFR / RC;
    constexpr int ROWS = BM + BN;
    constexpr int SLOTS = ROWS * 4;
    constexpr int GT = S * 64;
    constexpr int NL = SLOTS / GT;
    static_assert(SLOTS % GT == 0, "slot mapping must be exact");
    constexpr int STG = KG * ROWS * 64;
    constexpr int REDB = (KG > 1) ? (KG - 1) * S * RC * 64 * 16 : 0;
    constexpr int SMEM = STG > REDB ? STG : REDB;
    __shared__ __align__(16) char smem[SMEM];

    const int gx_ = gridDim.x;
    int b = blockIdx.x + gx_ * blockIdx.y;
    const int x = b & 7;
    int t = b >> 3;
    int ct, mt;
    if constexpr (NW == 2) {
        ct = (t & 3) * 8 + x; mt = t >> 2;
    } else {
        const int lo = t & 1; t >>= 1;
        ct = ((t & 3) * 8 + x) * 2 + lo; mt = t >> 2;
    }
    const int m0 = mt * BM;
    const int c0 = ct * BN;

    const int tid = threadIdx.x;
    const int lane = tid & 63;
    const int w = tid >> 6;
    const int kg = w / S;
    const int slot = w % S;
    const int wm = slot / NW;
    const int wn = slot % NW;

    const int Kc = 2048 / KG;
    const int kbeg = kg * Kc;

    u16* buf = (u16*)smem + (size_t)kg * ROWS * 32;

    const int gtid = slot * 64 + lane;
    const u16* gp[NL];
    u16* dl[NL];
    #pragma unroll
    for (int i = 0; i < NL; ++i) {
        const int s = gtid + i * GT;
        const int row = s >> 2;
        const int kof = (s & 3) * 8;
        if (row < BM) {
            int ar = m0 + row;
            if (ar >= n) ar = n - 1;
            gp[i] = A + (size_t)ar * 2048 + kbeg + kof;
        } else {
            gp[i] = Wp + (size_t)(c0 + row - BM) * 2048 + kbeg + kof;
        }
        dl[i] = buf + s * 8;
    }

    f32x4 acc[MI][4];
    #pragma unroll
    for (int mi = 0; mi < MI; ++mi)
        #pragma unroll
        for (int f = 0; f < 4; ++f)
            acc[mi][f] = f32x4{0.f, 0.f, 0.f, 0.f};

    const int fl = lane & 15;
    const int kb = (lane >> 4) * 8;
    const int ar0 = wm * MI * 16;
    const int bc0 = BM;

    for (int k0 = 0; k0 < Kc; k0 += 32) {
        #pragma unroll
        for (int i = 0; i < NL; ++i) { gload16(gp[i], dl[i]); gp[i] += 32; }
        __syncthreads();
        bf16x8 a_[MI], b_[4];
        #pragma unroll
        for (int mi = 0; mi < MI; ++mi)
            a_[mi] = *reinterpret_cast<const bf16x8*>(
                buf + (ar0 + mi * 16 + fl) * 32 + kb);
        #pragma unroll
        for (int f = 0; f < 4; ++f)
            b_[f] = *reinterpret_cast<const bf16x8*>(
                buf + (bc0 + wn * 64 + f * 16 + fl) * 32 + kb);
        #pragma unroll
        for (int mi = 0; mi < MI; ++mi)
            #pragma unroll
            for (int f = 0; f < 4; ++f)
                acc[mi][f] = __builtin_amdgcn_mfma_f32_16x16x32_bf16(
                    a_[mi], b_[f], acc[mi][f], 0, 0, 0);
        __syncthreads();
    }

    if constexpr (KG > 1) {
        f32x4* red = reinterpret_cast<f32x4*>(smem);
        #pragma unroll
        for (int pass = 0; pass < NP; ++pass) {
            if (kg > 0) {
                #pragma unroll
                for (int f = 0; f < RC; ++f) {
                    const int fr = pass * RC + f;
                    red[(((kg - 1) * S + slot) * RC + f) * 64 + lane] =
                        acc[fr >> 2][fr & 3];
                }
            }
            __syncthreads();
            if (kg == 0) {
                #pragma unroll
                for (int q = 1; q < KG; ++q)
                    #pragma unroll
                    for (int f = 0; f < RC; ++f) {
                        const int fr = pass * RC + f;
                        f32x4 v = red[(((q - 1) * S + slot) * RC + f) * 64 + lane];
                        acc[fr >> 2][fr & 3][0] += v[0];
                        acc[fr >> 2][fr & 3][1] += v[1];
                        acc[fr >> 2][fr & 3][2] += v[2];
                        acc[fr >> 2][fr & 3][3] += v[3];
                    }
            }
            __syncthreads();
        }
    }

    if (kg != 0) return;
    const int j = ((c0 + wn * 64) >> 6) * 16 + fl;
    #pragma unroll
    for (int mi = 0; mi < MI; ++mi) {
        #pragma unroll
        for (int r = 0; r < 4; ++r) {
            const int m = m0 + wm * MI * 16 + mi * 16 + (lane >> 4) * 4 + r;
            if (m >= n) continue;
            const u16* gx = GXl + (size_t)m * 4096 + c0 + wn * 64 + fl;
            const float i_ = acc[mi][0][r] + h2f(__builtin_nontemporal_load(gx));
            const float f_ = acc[mi][1][r] + h2f(__builtin_nontemporal_load(gx + 16));
            const float g_ = acc[mi][2][r] + h2f(__builtin_nontemporal_load(gx + 32));
            const float o_ = acc[mi][3][r] + h2f(__builtin_nontemporal_load(gx + 48));
            const float cc = __builtin_nontemporal_load(cprev + (size_t)m * 1024 + j);
            const float si = 1.0f / (1.0f + expf(-i_));
            const float sf = 1.0f / (1.0f + expf(-f_));
            const float so = 1.0f / (1.0f + expf(-o_));
            const float cn = sf * cc + si * tanhf(g_);
            const float hn = so * tanhf(cn);
            if (hnext)
                hnext[(size_t)(m >> 1) * 2048 + (m & 1) * 1024 + j] = f2bf(hn);
            if (!(m & 1))
                __builtin_nontemporal_store(cn, cnext + (size_t)(m >> 1) * 1024 + j);
            if (outp) { outp[j] = hn; outp[1024 + j] = cn; }
        }
    }
}

// ---------------------------------------------------------------- launcher
extern "C" void kernel_launch(void* const* d_in, const int* in_sizes, int n_in,
                              void* d_out, int out_size, void* d_ws, size_t ws_size,
                              hipStream_t stream) {
    const float* emb  = (const float*)d_in[0];
    const float* W_ih = (const float*)d_in[1];
    const float* W_hh = (const float*)d_in[2];
    const float* b_ih = (const float*)d_in[3];
    const float* b_hh = (const float*)d_in[4];
    float* out = (float*)d_out;

    char* p = (char*)d_ws;
    float* bge  = (float*)p;  p += 16384;
    u16* Wih_p  = (u16*)p;    p += (size_t)4096 * 1024 * 2;   //  8.4 MB
    u16* Whh_p  = (u16*)p;    p += (size_t)4096 * 2048 * 2;   // 16.8 MB
    u16* xb     = (u16*)p;    p += (size_t)4096 * 1024 * 2;   //  8.4 MB
    u16* GX     = (u16*)p;    p += (size_t)4096 * 4096 * 2;   // 33.6 MB (rows<2047 used)
    u16* Hcat   = (u16*)p;    p += (size_t)4096 * 2048 * 2;   // 16.8 MB
    float* cbA  = (float*)p;  p += (size_t)1024 * 1024 * 4;   //  4.2 MB
    float* cbB  = (float*)p;  p += (size_t)1024 * 1024 * 4;   //  4.2 MB

    bias_e_kernel<<<16, 256, 0, stream>>>(b_ih, b_hh, bge);
    pack_w<<<dim3(4096, 3), 256, 0, stream>>>(W_ih, W_hh, Wih_p, Whh_p);
    conv_emb<<<4095, 256, 0, stream>>>(emb, xb);

    #define OFF(k) (4096 - (2 << (k)))

    // GX (rows < 2047) + fused level-11 cell (rows >= 2047).
    gemm_gx<<<dim3(32, 32), 256, 0, stream>>>(
        xb, Wih_p, bge, GX, Hcat + (size_t)OFF(10) * 2048, cbA);

    const float* cprev = cbA;
    float* cbufs[2] = {cbB, cbA};
    int t = 0;
    for (int k = TREE_DEPTH - 2; k >= 0; --k) {
        const int n = 1 << k;
        const u16* A = Hcat + (size_t)OFF(k) * 2048;
        const u16* GXl = GX + (size_t)(n - 1) * 4096;
        u16* hnext = (k > 0) ? (Hcat + (size_t)OFF(k - 1) * 2048) : nullptr;
        float* cnext = cbufs[t];
        float* outp = (k == 0) ? out : nullptr;

        if (k == 10) {
            // BM=64, BN=128, KG=2, 256 thr: 512 blocks (2/CU).
            fused_level<4, 1, 2, 2><<<dim3(16, 32), 256, 0, stream>>>(
                A, Whh_p, GXl, cprev, hnext, cnext, outp, n);
        } else if (k == 9) {
            // BM=32, BN=128, KG=2, 256 thr: 512 blocks (2/CU).
            fused_level<2, 1, 2, 2><<<dim3(16, 32), 256, 0, stream>>>(
                A, Whh_p, GXl, cprev, hnext, cnext, outp, n);
        } else if (k == 8) {
            // BM=16, BN=64, KG=4, 256 thr: 1024 blocks (4/CU).
            fused_level<1, 1, 1, 4><<<dim3(16, 64), 256, 0, stream>>>(
                A, Whh_p, GXl, cprev, hnext, cnext, outp, n);
        } else {
            // BM=16, BN=64, KG=8, 512 thr: up to 512 blocks.
            const int gx = (n >= 16) ? n / 16 : 1;
            fused_level<1, 1, 1, 8><<<dim3(gx, 64), 512, 0, stream>>>(
                A, Whh_p, GXl, cprev, hnext, cnext, outp, n);
        }
        cprev = cnext; t ^= 1;
    }
}

// Round 15
// 259.762 us; speedup vs baseline: 3.0921x; 1.1051x over previous
//
#include <hip/hip_runtime.h>
#include <hip/hip_bf16.h>
#include <math.h>

// BinaryTreeLSTM — round 15: r14 + (a) gemm_gx BK=64 with source-pre-swizzle
// (o ^= (row&7)<<4 on BOTH global-src and ds_read side, rule #21) halving
// barrier drains, (b) merged prep kernel (bias+pack_w+conv_emb, one launch),
// (c) __expf-based fast sigmoid/tanh.
//
// Packed gate-interleaved column space: e = (j/16)*64 + g*16 + (j%16)
//   (orig W row g*2048+j). Wih_p[4096][1024], Whh_p[4096][2048] bf16,
//   XCD-affine 128-row tiles: tile (e>>7) written by blocks with b&7==(e>>7)%8.
// GX[4096][4096] fp16: rows 0..2046 = bf16(emb[node]) @ Wih_p^T + bge;
//   rows >= 2047 (level-11) consumed in-register by the gemm_gx epilogue.
// Hcat: level-k h-slab at row OFF(k)=4096-2^(k+1), 2^k rows x 2048 bf16.
// c compact: level k writes even-node c at row m>>1 (1024 f32); k-1 reads row m.

#define TREE_DEPTH 12

typedef unsigned short u16;
typedef unsigned int u32;
typedef __attribute__((ext_vector_type(8))) short bf16x8;
typedef __attribute__((ext_vector_type(4))) float f32x4;
typedef __attribute__((ext_vector_type(8))) unsigned short u16x8;
typedef __attribute__((ext_vector_type(2))) unsigned int u32x2;

__device__ __forceinline__ void gload16(const void* g, void* l) {
    __builtin_amdgcn_global_load_lds(
        (const __attribute__((address_space(1))) u32*)g,
        (__attribute__((address_space(3))) u32*)l, 16, 0, 0);
}

__device__ __forceinline__ u16 f2bf(float f) {
    __hip_bfloat16 h = __float2bfloat16(f);
    return *reinterpret_cast<u16*>(&h);
}
__device__ __forceinline__ u16 f2h(float f) {
    _Float16 h = (_Float16)f;
    return *reinterpret_cast<u16*>(&h);
}
__device__ __forceinline__ float h2f(u16 u) {
    _Float16 h;
    *reinterpret_cast<u16*>(&h) = u;
    return (float)h;
}
__device__ __forceinline__ float fsig(float x) {
    return 1.0f / (1.0f + __expf(-x));
}
__device__ __forceinline__ float ftanh(float x) {
    return 1.0f - 2.0f / (1.0f + __expf(2.0f * x));
}

// ---------------------------------------------------------------- prep
// One kernel: blocks [0,12288) pack weights, [12288,16383) convert emb,
// [16383,16399) fuse bias.
__global__ void prep(const float* __restrict__ Wih,
                     const float* __restrict__ Whh,
                     const float* __restrict__ emb,
                     const float* __restrict__ b_ih,
                     const float* __restrict__ b_hh,
                     u16* __restrict__ Wih_p, u16* __restrict__ Whh_p,
                     u16* __restrict__ xb, float* __restrict__ bge) {
    const int bid = blockIdx.x;
    if (bid < 12288) {
        const int b = bid & 4095;
        const int seg = bid >> 12;         // 0: ih, 1/2: hh halves
        const int x = b & 7, t = b >> 3;   // t in [0,512)
        const int e = ((t & 3) * 8 + x) * 128 + (t >> 2);  // (e>>7)%8 == x
        const int g = (e >> 4) & 3;
        const int j = (e >> 6) * 16 + (e & 15);
        const int wr = g * 2048 + j;
        const int col = threadIdx.x * 4;
        f32x4 v;
        u16* dst;
        if (seg == 0) {
            v = __builtin_nontemporal_load(
                (const f32x4*)(Wih + (size_t)wr * 1024 + col));
            dst = Wih_p + (size_t)e * 1024 + col;
        } else {
            v = __builtin_nontemporal_load(
                (const f32x4*)(Whh + (size_t)wr * 2048 + (seg - 1) * 1024 + col));
            dst = Whh_p + (size_t)e * 2048 + (seg - 1) * 1024 + col;
        }
        u32x2 p;
        p[0] = (u32)f2bf(v[0]) | ((u32)f2bf(v[1]) << 16);
        p[1] = (u32)f2bf(v[2]) | ((u32)f2bf(v[3]) << 16);
        *reinterpret_cast<u32x2*>(dst) = p;
    } else if (bid < 16383) {
        size_t idx = ((size_t)(bid - 12288) * 256 + threadIdx.x) * 4;
        f32x4 v = __builtin_nontemporal_load((const f32x4*)(emb + idx));
        u32x2 p;
        p[0] = (u32)f2bf(v[0]) | ((u32)f2bf(v[1]) << 16);
        p[1] = (u32)f2bf(v[2]) | ((u32)f2bf(v[3]) << 16);
        *reinterpret_cast<u32x2*>(xb + idx) = p;
    } else {
        int e = (bid - 16383) * 256 + threadIdx.x;   // 0..4095 packed order
        int g = (e >> 4) & 3;
        int j = (e >> 6) * 16 + (e & 15);
        int r = g * 2048 + j;
        bge[e] = b_ih[r] + b_hh[r];
    }
}

// ---------------------------------------------------------------- GX GEMM
// Rows < 2047: GX fp16 (LDS-staged store). Rows >= 2047: level-11 cell.
// 128x128 tile, 4 waves, BK=64 (16 barrier pairs, 32 MFMA each).
// LDS rows are 128B; both source addressing and ds_read XOR byte offset
// with ((row&7)<<4) -> ~2-way bank conflicts.
__global__ __launch_bounds__(256) void gemm_gx(
    const u16* __restrict__ xb, const u16* __restrict__ Wp,
    const float* __restrict__ bge, u16* __restrict__ GX,
    u16* __restrict__ hdst, float* __restrict__ cdst)
{
    __shared__ u16 smem[128 * 140];   // staging uses [0, 256*64) u16

    const int gx_ = gridDim.x;   // 32
    int b = blockIdx.x + gx_ * blockIdx.y;
    const int x = b & 7, t = b >> 3;
    const int ct = (t & 3) * 8 + x;
    const int mt = t >> 2;
    const int m0 = mt * 128, c0 = ct * 128;

    const int tid = threadIdx.x, lane = tid & 63, w = tid >> 6;
    const int wr = (w >> 1) * 64, wc = (w & 1) * 64;

    f32x4 acc[4][4];
    #pragma unroll
    for (int i = 0; i < 4; ++i)
        #pragma unroll
        for (int j = 0; j < 4; ++j)
            acc[i][j] = f32x4{0.f, 0.f, 0.f, 0.f};

    // staging: 2048 slots x 16B; slot s -> LDS row s>>3, byte (s&7)*16.
    // source element pre-swizzled so swizzled ds_read sees identity.
    const u16* gp[8];
    u16* dl[8];
    #pragma unroll
    for (int i = 0; i < 8; ++i) {
        const int s = tid + i * 256;
        const int r = s >> 3;
        const int o = (s & 7) * 16;
        const int ke = (o ^ ((r & 7) << 4)) >> 1;   // element offset 0..63
        gp[i] = (r < 128) ? xb + (size_t)(m0 + r) * 1024 + ke
                          : Wp + (size_t)(c0 + r - 128) * 1024 + ke;
        dl[i] = smem + s * 8;
    }

    const int fl = lane & 15;
    const int kunit = (lane >> 4) * 16;   // byte offset of fragment in k-chunk

    for (int k0 = 0; k0 < 1024; k0 += 64) {
        #pragma unroll
        for (int i = 0; i < 8; ++i) { gload16(gp[i], dl[i]); gp[i] += 64; }
        __syncthreads();
        #pragma unroll
        for (int ks = 0; ks < 2; ++ks) {
            bf16x8 a_[4], b_[4];
            #pragma unroll
            for (int i = 0; i < 4; ++i) {
                const int ar = wr + i * 16 + fl;
                const int byo = (ks * 64 + kunit) ^ ((ar & 7) << 4);
                a_[i] = *reinterpret_cast<const bf16x8*>(
                    reinterpret_cast<const char*>(smem + ar * 64) + byo);
            }
            #pragma unroll
            for (int j = 0; j < 4; ++j) {
                const int br = 128 + wc + j * 16 + fl;
                const int byo = (ks * 64 + kunit) ^ ((br & 7) << 4);
                b_[j] = *reinterpret_cast<const bf16x8*>(
                    reinterpret_cast<const char*>(smem + br * 64) + byo);
            }
            #pragma unroll
            for (int i = 0; i < 4; ++i)
                #pragma unroll
                for (int j = 0; j < 4; ++j)
                    acc[i][j] = __builtin_amdgcn_mfma_f32_16x16x32_bf16(
                        a_[i], b_[j], acc[i][j], 0, 0, 0);
        }
        __syncthreads();
    }

    const int rg = (lane >> 4) * 4;
    if (m0 < 2047) {
        // stage C (fp16 + bias) in LDS (stride 140), coalesced 16B stores
        #pragma unroll
        for (int i = 0; i < 4; ++i)
            #pragma unroll
            for (int j = 0; j < 4; ++j) {
                const float bv = bge[c0 + wc + j * 16 + fl];
                #pragma unroll
                for (int r = 0; r < 4; ++r)
                    smem[(wr + i * 16 + rg + r) * 140 + (wc + j * 16 + fl)] =
                        f2h(acc[i][j][r] + bv);
            }
        __syncthreads();
        const int row_ = tid >> 4, chunk = tid & 15;
        #pragma unroll
        for (int it = 0; it < 8; ++it) {
            const int row = it * 16 + row_;
            if (m0 + row < 2047) {
                u16x8 v = *reinterpret_cast<const u16x8*>(
                    &smem[row * 140 + chunk * 8]);
                __builtin_nontemporal_store(
                    v, (u16x8*)(GX + (size_t)(m0 + row) * 4096 + c0 + chunk * 8));
            }
        }
    }
    if (m0 + 127 >= 2047) {
        // level-11 LSTM cell: c_prev = 0, f-gate unused.
        const int jj = ((c0 + wc) >> 6) * 16 + fl;
        const float bi  = bge[c0 + wc + fl];
        const float bgg = bge[c0 + wc + 32 + fl];
        const float bo  = bge[c0 + wc + 48 + fl];
        #pragma unroll
        for (int i = 0; i < 4; ++i) {
            #pragma unroll
            for (int r = 0; r < 4; ++r) {
                const int m = m0 + wr + i * 16 + rg + r;
                if (m < 2047 || m >= 4095) continue;
                const int mm = m - 2047;
                const float cn = fsig(acc[i][0][r] + bi) * ftanh(acc[i][2][r] + bgg);
                const float hn = fsig(acc[i][3][r] + bo) * ftanh(cn);
                hdst[(size_t)(mm >> 1) * 2048 + (mm & 1) * 1024 + jj] = f2bf(hn);
                if (!(mm & 1))
                    cdst[(size_t)(mm >> 1) * 1024 + jj] = cn;
            }
        }
    }
}

// ---------------------------------------------------------------- fused level
// gates = A(h_cat) @ Whh_p^T + GX[node]; K=2048 split KG ways in-block.
template <int MI, int MW, int NW, int KG>
__global__ __launch_bounds__(MW* NW* KG * 64) void fused_level(
    const u16* __restrict__ A, const u16* __restrict__ Wp,
    const u16* __restrict__ GXl, const float* __restrict__ cprev,
    u16* __restrict__ hnext, float* __restrict__ cnext,
    float* __restrict__ outp, int n)
{
    constexpr int BM = MI * 16 * MW;
    constexpr int BN = NW * 64;
    constexpr int S = MW * NW;
    constexpr int NFR = MI * 4;
    constexpr int RC = NFR > 8 ? 8 : NFR;
    constexpr int NP = NFR / RC;
    constexpr int ROWS = BM + BN;
    constexpr int SLOTS = ROWS * 4;
    constexpr int GT = S * 64;
    constexpr int NL = SLOTS / GT;
    static_assert(SLOTS % GT == 0, "slot mapping must be exact");
    constexpr int STG = KG * ROWS * 64;
    constexpr int REDB = (KG > 1) ? (KG - 1) * S * RC * 64 * 16 : 0;
    constexpr int SMEM = STG > REDB ? STG : REDB;
    __shared__ __align__(16) char smem[SMEM];

    const int gx_ = gridDim.x;
    int b = blockIdx.x + gx_ * blockIdx.y;
    const int x = b & 7;
    int t = b >> 3;
    int ct, mt;
    if constexpr (NW == 2) {
        ct = (t & 3) * 8 + x; mt = t >> 2;
    } else {
        const int lo = t & 1; t >>= 1;
        ct = ((t & 3) * 8 + x) * 2 + lo; mt = t >> 2;
    }
    const int m0 = mt * BM;
    const int c0 = ct * BN;

    const int tid = threadIdx.x;
    const int lane = tid & 63;
    const int w = tid >> 6;
    const int kg = w / S;
    const int slot = w % S;
    const int wm = slot / NW;
    const int wn = slot % NW;

    const int Kc = 2048 / KG;
    const int kbeg = kg * Kc;

    u16* buf = (u16*)smem + (size_t)kg * ROWS * 32;

    const int gtid = slot * 64 + lane;
    const u16* gp[NL];
    u16* dl[NL];
    #pragma unroll
    for (int i = 0; i < NL; ++i) {
        const int s = gtid + i * GT;
        const int row = s >> 2;
        const int kof = (s & 3) * 8;
        if (row < BM) {
            int ar = m0 + row;
            if (ar >= n) ar = n - 1;
            gp[i] = A + (size_t)ar * 2048 + kbeg + kof;
        } else {
            gp[i] = Wp + (size_t)(c0 + row - BM) * 2048 + kbeg + kof;
        }
        dl[i] = buf + s * 8;
    }

    f32x4 acc[MI][4];
    #pragma unroll
    for (int mi = 0; mi < MI; ++mi)
        #pragma unroll
        for (int f = 0; f < 4; ++f)
            acc[mi][f] = f32x4{0.f, 0.f, 0.f, 0.f};

    const int fl = lane & 15;
    const int kb = (lane >> 4) * 8;
    const int ar0 = wm * MI * 16;
    const int bc0 = BM;

    for (int k0 = 0; k0 < Kc; k0 += 32) {
        #pragma unroll
        for (int i = 0; i < NL; ++i) { gload16(gp[i], dl[i]); gp[i] += 32; }
        __syncthreads();
        bf16x8 a_[MI], b_[4];
        #pragma unroll
        for (int mi = 0; mi < MI; ++mi)
            a_[mi] = *reinterpret_cast<const bf16x8*>(
                buf + (ar0 + mi * 16 + fl) * 32 + kb);
        #pragma unroll
        for (int f = 0; f < 4; ++f)
            b_[f] = *reinterpret_cast<const bf16x8*>(
                buf + (bc0 + wn * 64 + f * 16 + fl) * 32 + kb);
        #pragma unroll
        for (int mi = 0; mi < MI; ++mi)
            #pragma unroll
            for (int f = 0; f < 4; ++f)
                acc[mi][f] = __builtin_amdgcn_mfma_f32_16x16x32_bf16(
                    a_[mi], b_[f], acc[mi][f], 0, 0, 0);
        __syncthreads();
    }

    if constexpr (KG > 1) {
        f32x4* red = reinterpret_cast<f32x4*>(smem);
        #pragma unroll
        for (int pass = 0; pass < NP; ++pass) {
            if (kg > 0) {
                #pragma unroll
                for (int f = 0; f < RC; ++f) {
                    const int fr = pass * RC + f;
                    red[(((kg - 1) * S + slot) * RC + f) * 64 + lane] =
                        acc[fr >> 2][fr & 3];
                }
            }
            __syncthreads();
            if (kg == 0) {
                #pragma unroll
                for (int q = 1; q < KG; ++q)
                    #pragma unroll
                    for (int f = 0; f < RC; ++f) {
                        const int fr = pass * RC + f;
                        f32x4 v = red[(((q - 1) * S + slot) * RC + f) * 64 + lane];
                        acc[fr >> 2][fr & 3][0] += v[0];
                        acc[fr >> 2][fr & 3][1] += v[1];
                        acc[fr >> 2][fr & 3][2] += v[2];
                        acc[fr >> 2][fr & 3][3] += v[3];
                    }
            }
            __syncthreads();
        }
    }

    if (kg != 0) return;
    const int j = ((c0 + wn * 64) >> 6) * 16 + fl;
    #pragma unroll
    for (int mi = 0; mi < MI; ++mi) {
        #pragma unroll
        for (int r = 0; r < 4; ++r) {
            const int m = m0 + wm * MI * 16 + mi * 16 + (lane >> 4) * 4 + r;
            if (m >= n) continue;
            const u16* gx = GXl + (size_t)m * 4096 + c0 + wn * 64 + fl;
            const float i_ = acc[mi][0][r] + h2f(__builtin_nontemporal_load(gx));
            const float f_ = acc[mi][1][r] + h2f(__builtin_nontemporal_load(gx + 16));
            const float g_ = acc[mi][2][r] + h2f(__builtin_nontemporal_load(gx + 32));
            const float o_ = acc[mi][3][r] + h2f(__builtin_nontemporal_load(gx + 48));
            const float cc = __builtin_nontemporal_load(cprev + (size_t)m * 1024 + j);
            const float cn = fsig(f_) * cc + fsig(i_) * ftanh(g_);
            const float hn = fsig(o_) * ftanh(cn);
            if (hnext)
                hnext[(size_t)(m >> 1) * 2048 + (m & 1) * 1024 + j] = f2bf(hn);
            if (!(m & 1))
                __builtin_nontemporal_store(cn, cnext + (size_t)(m >> 1) * 1024 + j);
            if (outp) { outp[j] = hn; outp[1024 + j] = cn; }
        }
    }
}

// ---------------------------------------------------------------- launcher
extern "C" void kernel_launch(void* const* d_in, const int* in_sizes, int n_in,
                              void* d_out, int out_size, void* d_ws, size_t ws_size,
                              hipStream_t stream) {
    const float* emb  = (const float*)d_in[0];
    const float* W_ih = (const float*)d_in[1];
    const float* W_hh = (const float*)d_in[2];
    const float* b_ih = (const float*)d_in[3];
    const float* b_hh = (const float*)d_in[4];
    float* out = (float*)d_out;

    char* p = (char*)d_ws;
    float* bge  = (float*)p;  p += 16384;
    u16* Wih_p  = (u16*)p;    p += (size_t)4096 * 1024 * 2;   //  8.4 MB
    u16* Whh_p  = (u16*)p;    p += (size_t)4096 * 2048 * 2;   // 16.8 MB
    u16* xb     = (u16*)p;    p += (size_t)4096 * 1024 * 2;   //  8.4 MB
    u16* GX     = (u16*)p;    p += (size_t)4096 * 4096 * 2;   // 33.6 MB (rows<2047 used)
    u16* Hcat   = (u16*)p;    p += (size_t)4096 * 2048 * 2;   // 16.8 MB
    float* cbA  = (float*)p;  p += (size_t)1024 * 1024 * 4;   //  4.2 MB
    float* cbB  = (float*)p;  p += (size_t)1024 * 1024 * 4;   //  4.2 MB

    prep<<<16399, 256, 0, stream>>>(W_ih, W_hh, emb, b_ih, b_hh,
                                    Wih_p, Whh_p, xb, bge);

    #define OFF(k) (4096 - (2 << (k)))

    // GX (rows < 2047) + fused level-11 cell (rows >= 2047).
    gemm_gx<<<dim3(32, 32), 256, 0, stream>>>(
        xb, Wih_p, bge, GX, Hcat + (size_t)OFF(10) * 2048, cbA);

    const float* cprev = cbA;
    float* cbufs[2] = {cbB, cbA};
    int t = 0;
    for (int k = TREE_DEPTH - 2; k >= 0; --k) {
        const int n = 1 << k;
        const u16* A = Hcat + (size_t)OFF(k) * 2048;
        const u16* GXl = GX + (size_t)(n - 1) * 4096;
        u16* hnext = (k > 0) ? (Hcat + (size_t)OFF(k - 1) * 2048) : nullptr;
        float* cnext = cbufs[t];
        float* outp = (k == 0) ? out : nullptr;

        if (k == 10) {
            // BM=64, BN=128, KG=2, 256 thr: 512 blocks (2/CU).
            fused_level<4, 1, 2, 2><<<dim3(16, 32), 256, 0, stream>>>(
                A, Whh_p, GXl, cprev, hnext, cnext, outp, n);
        } else if (k == 9) {
            // BM=32, BN=128, KG=2, 256 thr: 512 blocks (2/CU).
            fused_level<2, 1, 2, 2><<<dim3(16, 32), 256, 0, stream>>>(
                A, Whh_p, GXl, cprev, hnext, cnext, outp, n);
        } else if (k == 8) {
            // BM=16, BN=64, KG=4, 256 thr: 1024 blocks (4/CU).
            fused_level<1, 1, 1, 4><<<dim3(16, 64), 256, 0, stream>>>(
                A, Whh_p, GXl, cprev, hnext, cnext, outp, n);
        } else {
            // BM=16, BN=64, KG=8, 512 thr: up to 512 blocks.
            const int gx = (n >= 16) ? n / 16 : 1;
            fused_level<1, 1, 1, 8><<<dim3(gx, 64), 512, 0, stream>>>(
                A, Whh_p, GXl, cprev, hnext, cnext, outp, n);
        }
        cprev = cnext; t ^= 1;
    }
}

// Round 16
// 220.994 us; speedup vs baseline: 3.6345x; 1.1754x over previous
//
#include <hip/hip_runtime.h>
#include <hip/hip_bf16.h>
#include <math.h>

// BinaryTreeLSTM — round 16: r15 + BK=64 both-sides-swizzled staging applied
// to fused_level (the r15 gemm_gx treatment: halved barrier drains, 32 MFMA
// per barrier pair, bank-conflict-free ds_read_b128).
//
// Packed gate-interleaved column space: e = (j/16)*64 + g*16 + (j%16)
//   (orig W row g*2048+j). Wih_p[4096][1024], Whh_p[4096][2048] bf16,
//   XCD-affine 128-row tiles: tile (e>>7) written by blocks with b&7==(e>>7)%8.
// GX[4096][4096] fp16: rows 0..2046 = bf16(emb[node]) @ Wih_p^T + bge;
//   rows >= 2047 (level-11) consumed in-register by the gemm_gx epilogue.
// Hcat: level-k h-slab at row OFF(k)=4096-2^(k+1), 2^k rows x 2048 bf16.
// c compact: level k writes even-node c at row m>>1 (1024 f32); k-1 reads row m.

#define TREE_DEPTH 12

typedef unsigned short u16;
typedef unsigned int u32;
typedef __attribute__((ext_vector_type(8))) short bf16x8;
typedef __attribute__((ext_vector_type(4))) float f32x4;
typedef __attribute__((ext_vector_type(8))) unsigned short u16x8;
typedef __attribute__((ext_vector_type(2))) unsigned int u32x2;

__device__ __forceinline__ void gload16(const void* g, void* l) {
    __builtin_amdgcn_global_load_lds(
        (const __attribute__((address_space(1))) u32*)g,
        (__attribute__((address_space(3))) u32*)l, 16, 0, 0);
}

__device__ __forceinline__ u16 f2bf(float f) {
    __hip_bfloat16 h = __float2bfloat16(f);
    return *reinterpret_cast<u16*>(&h);
}
__device__ __forceinline__ u16 f2h(float f) {
    _Float16 h = (_Float16)f;
    return *reinterpret_cast<u16*>(&h);
}
__device__ __forceinline__ float h2f(u16 u) {
    _Float16 h;
    *reinterpret_cast<u16*>(&h) = u;
    return (float)h;
}
__device__ __forceinline__ float fsig(float x) {
    return 1.0f / (1.0f + __expf(-x));
}
__device__ __forceinline__ float ftanh(float x) {
    return 1.0f - 2.0f / (1.0f + __expf(2.0f * x));
}

// ---------------------------------------------------------------- prep
__global__ void prep(const float* __restrict__ Wih,
                     const float* __restrict__ Whh,
                     const float* __restrict__ emb,
                     const float* __restrict__ b_ih,
                     const float* __restrict__ b_hh,
                     u16* __restrict__ Wih_p, u16* __restrict__ Whh_p,
                     u16* __restrict__ xb, float* __restrict__ bge) {
    const int bid = blockIdx.x;
    if (bid < 12288) {
        const int b = bid & 4095;
        const int seg = bid >> 12;         // 0: ih, 1/2: hh halves
        const int x = b & 7, t = b >> 3;   // t in [0,512)
        const int e = ((t & 3) * 8 + x) * 128 + (t >> 2);  // (e>>7)%8 == x
        const int g = (e >> 4) & 3;
        const int j = (e >> 6) * 16 + (e & 15);
        const int wr = g * 2048 + j;
        const int col = threadIdx.x * 4;
        f32x4 v;
        u16* dst;
        if (seg == 0) {
            v = __builtin_nontemporal_load(
                (const f32x4*)(Wih + (size_t)wr * 1024 + col));
            dst = Wih_p + (size_t)e * 1024 + col;
        } else {
            v = __builtin_nontemporal_load(
                (const f32x4*)(Whh + (size_t)wr * 2048 + (seg - 1) * 1024 + col));
            dst = Whh_p + (size_t)e * 2048 + (seg - 1) * 1024 + col;
        }
        u32x2 p;
        p[0] = (u32)f2bf(v[0]) | ((u32)f2bf(v[1]) << 16);
        p[1] = (u32)f2bf(v[2]) | ((u32)f2bf(v[3]) << 16);
        *reinterpret_cast<u32x2*>(dst) = p;
    } else if (bid < 16383) {
        size_t idx = ((size_t)(bid - 12288) * 256 + threadIdx.x) * 4;
        f32x4 v = __builtin_nontemporal_load((const f32x4*)(emb + idx));
        u32x2 p;
        p[0] = (u32)f2bf(v[0]) | ((u32)f2bf(v[1]) << 16);
        p[1] = (u32)f2bf(v[2]) | ((u32)f2bf(v[3]) << 16);
        *reinterpret_cast<u32x2*>(xb + idx) = p;
    } else {
        int e = (bid - 16383) * 256 + threadIdx.x;   // 0..4095 packed order
        int g = (e >> 4) & 3;
        int j = (e >> 6) * 16 + (e & 15);
        int r = g * 2048 + j;
        bge[e] = b_ih[r] + b_hh[r];
    }
}

// ---------------------------------------------------------------- GX GEMM
// Rows < 2047: GX fp16 (LDS-staged store). Rows >= 2047: level-11 cell.
// 128x128 tile, 4 waves, BK=64 swizzled (r15-proven).
__global__ __launch_bounds__(256) void gemm_gx(
    const u16* __restrict__ xb, const u16* __restrict__ Wp,
    const float* __restrict__ bge, u16* __restrict__ GX,
    u16* __restrict__ hdst, float* __restrict__ cdst)
{
    __shared__ u16 smem[128 * 140];   // staging uses [0, 256*64) u16

    const int gx_ = gridDim.x;   // 32
    int b = blockIdx.x + gx_ * blockIdx.y;
    const int x = b & 7, t = b >> 3;
    const int ct = (t & 3) * 8 + x;
    const int mt = t >> 2;
    const int m0 = mt * 128, c0 = ct * 128;

    const int tid = threadIdx.x, lane = tid & 63, w = tid >> 6;
    const int wr = (w >> 1) * 64, wc = (w & 1) * 64;

    f32x4 acc[4][4];
    #pragma unroll
    for (int i = 0; i < 4; ++i)
        #pragma unroll
        for (int j = 0; j < 4; ++j)
            acc[i][j] = f32x4{0.f, 0.f, 0.f, 0.f};

    const u16* gp[8];
    u16* dl[8];
    #pragma unroll
    for (int i = 0; i < 8; ++i) {
        const int s = tid + i * 256;
        const int r = s >> 3;
        const int o = (s & 7) * 16;
        const int ke = (o ^ ((r & 7) << 4)) >> 1;   // element offset 0..63
        gp[i] = (r < 128) ? xb + (size_t)(m0 + r) * 1024 + ke
                          : Wp + (size_t)(c0 + r - 128) * 1024 + ke;
        dl[i] = smem + s * 8;
    }

    const int fl = lane & 15;
    const int kunit = (lane >> 4) * 16;   // byte offset of fragment in k-chunk

    for (int k0 = 0; k0 < 1024; k0 += 64) {
        #pragma unroll
        for (int i = 0; i < 8; ++i) { gload16(gp[i], dl[i]); gp[i] += 64; }
        __syncthreads();
        #pragma unroll
        for (int ks = 0; ks < 2; ++ks) {
            bf16x8 a_[4], b_[4];
            #pragma unroll
            for (int i = 0; i < 4; ++i) {
                const int ar = wr + i * 16 + fl;
                const int byo = (ks * 64 + kunit) ^ ((ar & 7) << 4);
                a_[i] = *reinterpret_cast<const bf16x8*>(
                    reinterpret_cast<const char*>(smem + ar * 64) + byo);
            }
            #pragma unroll
            for (int j = 0; j < 4; ++j) {
                const int br = 128 + wc + j * 16 + fl;
                const int byo = (ks * 64 + kunit) ^ ((br & 7) << 4);
                b_[j] = *reinterpret_cast<const bf16x8*>(
                    reinterpret_cast<const char*>(smem + br * 64) + byo);
            }
            #pragma unroll
            for (int i = 0; i < 4; ++i)
                #pragma unroll
                for (int j = 0; j < 4; ++j)
                    acc[i][j] = __builtin_amdgcn_mfma_f32_16x16x32_bf16(
                        a_[i], b_[j], acc[i][j], 0, 0, 0);
        }
        __syncthreads();
    }

    const int rg = (lane >> 4) * 4;
    if (m0 < 2047) {
        #pragma unroll
        for (int i = 0; i < 4; ++i)
            #pragma unroll
            for (int j = 0; j < 4; ++j) {
                const float bv = bge[c0 + wc + j * 16 + fl];
                #pragma unroll
                for (int r = 0; r < 4; ++r)
                    smem[(wr + i * 16 + rg + r) * 140 + (wc + j * 16 + fl)] =
                        f2h(acc[i][j][r] + bv);
            }
        __syncthreads();
        const int row_ = tid >> 4, chunk = tid & 15;
        #pragma unroll
        for (int it = 0; it < 8; ++it) {
            const int row = it * 16 + row_;
            if (m0 + row < 2047) {
                u16x8 v = *reinterpret_cast<const u16x8*>(
                    &smem[row * 140 + chunk * 8]);
                __builtin_nontemporal_store(
                    v, (u16x8*)(GX + (size_t)(m0 + row) * 4096 + c0 + chunk * 8));
            }
        }
    }
    if (m0 + 127 >= 2047) {
        const int jj = ((c0 + wc) >> 6) * 16 + fl;
        const float bi  = bge[c0 + wc + fl];
        const float bgg = bge[c0 + wc + 32 + fl];
        const float bo  = bge[c0 + wc + 48 + fl];
        #pragma unroll
        for (int i = 0; i < 4; ++i) {
            #pragma unroll
            for (int r = 0; r < 4; ++r) {
                const int m = m0 + wr + i * 16 + rg + r;
                if (m < 2047 || m >= 4095) continue;
                const int mm = m - 2047;
                const float cn = fsig(acc[i][0][r] + bi) * ftanh(acc[i][2][r] + bgg);
                const float hn = fsig(acc[i][3][r] + bo) * ftanh(cn);
                hdst[(size_t)(mm >> 1) * 2048 + (mm & 1) * 1024 + jj] = f2bf(hn);
                if (!(mm & 1))
                    cdst[(size_t)(mm >> 1) * 1024 + jj] = cn;
            }
        }
    }
}

// ---------------------------------------------------------------- fused level
// gates = A(h_cat) @ Whh_p^T + GX[node]; K=2048 split KG ways in-block.
// BK=64, both-sides-swizzled LDS (128B rows, byte ^= (row&7)<<4).
template <int MI, int MW, int NW, int KG>
__global__ __launch_bounds__(MW* NW* KG * 64) void fused_level(
    const u16* __restrict__ A, const u16* __restrict__ Wp,
    const u16* __restrict__ GXl, const float* __restrict__ cprev,
    u16* __restrict__ hnext, float* __restrict__ cnext,
    float* __restrict__ outp, int n)
{
    constexpr int BM = MI * 16 * MW;
    constexpr int BN = NW * 64;
    constexpr int S = MW * NW;
    constexpr int NFR = MI * 4;
    constexpr int RC = NFR > 8 ? 8 : NFR;
    constexpr int NP = NFR / RC;
    constexpr int ROWS = BM + BN;
    constexpr int SLOTS = ROWS * 8;       // 16B slots per BK=64 step
    constexpr int GT = S * 64;
    constexpr int NL = SLOTS / GT;
    static_assert(SLOTS % GT == 0, "slot mapping must be exact");
    constexpr int STG = KG * ROWS * 128;
    constexpr int REDB = (KG > 1) ? (KG - 1) * S * RC * 64 * 16 : 0;
    constexpr int SMEM = STG > REDB ? STG : REDB;
    __shared__ __align__(16) char smem[SMEM];

    const int gx_ = gridDim.x;
    int b = blockIdx.x + gx_ * blockIdx.y;
    const int x = b & 7;
    int t = b >> 3;
    int ct, mt;
    if constexpr (NW == 2) {
        ct = (t & 3) * 8 + x; mt = t >> 2;
    } else {
        const int lo = t & 1; t >>= 1;
        ct = ((t & 3) * 8 + x) * 2 + lo; mt = t >> 2;
    }
    const int m0 = mt * BM;
    const int c0 = ct * BN;

    const int tid = threadIdx.x;
    const int lane = tid & 63;
    const int w = tid >> 6;
    const int kg = w / S;
    const int slot = w % S;
    const int wm = slot / NW;
    const int wn = slot % NW;

    const int Kc = 2048 / KG;
    const int kbeg = kg * Kc;

    u16* buf = (u16*)smem + (size_t)kg * ROWS * 64;

    // staging: slot s -> LDS row s>>3, byte (s&7)*16; source pre-swizzled.
    const int gtid = slot * 64 + lane;
    const u16* gp[NL];
    u16* dl[NL];
    #pragma unroll
    for (int i = 0; i < NL; ++i) {
        const int s = gtid + i * GT;
        const int r = s >> 3;
        const int o = (s & 7) * 16;
        const int ke = (o ^ ((r & 7) << 4)) >> 1;   // element 0..63
        if (r < BM) {
            int ar = m0 + r;
            if (ar >= n) ar = n - 1;
            gp[i] = A + (size_t)ar * 2048 + kbeg + ke;
        } else {
            gp[i] = Wp + (size_t)(c0 + r - BM) * 2048 + kbeg + ke;
        }
        dl[i] = buf + s * 8;
    }

    f32x4 acc[MI][4];
    #pragma unroll
    for (int mi = 0; mi < MI; ++mi)
        #pragma unroll
        for (int f = 0; f < 4; ++f)
            acc[mi][f] = f32x4{0.f, 0.f, 0.f, 0.f};

    const int fl = lane & 15;
    const int kunit = (lane >> 4) * 16;
    const int ar0 = wm * MI * 16;
    const int bc0 = BM;

    for (int k0 = 0; k0 < Kc; k0 += 64) {
        #pragma unroll
        for (int i = 0; i < NL; ++i) { gload16(gp[i], dl[i]); gp[i] += 64; }
        __syncthreads();
        #pragma unroll
        for (int ks = 0; ks < 2; ++ks) {
            bf16x8 a_[MI], b_[4];
            #pragma unroll
            for (int mi = 0; mi < MI; ++mi) {
                const int ar = ar0 + mi * 16 + fl;
                const int byo = (ks * 64 + kunit) ^ ((ar & 7) << 4);
                a_[mi] = *reinterpret_cast<const bf16x8*>(
                    reinterpret_cast<const char*>(buf + ar * 64) + byo);
            }
            #pragma unroll
            for (int f = 0; f < 4; ++f) {
                const int br = bc0 + wn * 64 + f * 16 + fl;
                const int byo = (ks * 64 + kunit) ^ ((br & 7) << 4);
                b_[f] = *reinterpret_cast<const bf16x8*>(
                    reinterpret_cast<const char*>(buf + br * 64) + byo);
            }
            #pragma unroll
            for (int mi = 0; mi < MI; ++mi)
                #pragma unroll
                for (int f = 0; f < 4; ++f)
                    acc[mi][f] = __builtin_amdgcn_mfma_f32_16x16x32_bf16(
                        a_[mi], b_[f], acc[mi][f], 0, 0, 0);
        }
        __syncthreads();
    }

    if constexpr (KG > 1) {
        f32x4* red = reinterpret_cast<f32x4*>(smem);
        #pragma unroll
        for (int pass = 0; pass < NP; ++pass) {
            if (kg > 0) {
                #pragma unroll
                for (int f = 0; f < RC; ++f) {
                    const int fr = pass * RC + f;
                    red[(((kg - 1) * S + slot) * RC + f) * 64 + lane] =
                        acc[fr >> 2][fr & 3];
                }
            }
            __syncthreads();
            if (kg == 0) {
                #pragma unroll
                for (int q = 1; q < KG; ++q)
                    #pragma unroll
                    for (int f = 0; f < RC; ++f) {
                        const int fr = pass * RC + f;
                        f32x4 v = red[(((q - 1) * S + slot) * RC + f) * 64 + lane];
                        acc[fr >> 2][fr & 3][0] += v[0];
                        acc[fr >> 2][fr & 3][1] += v[1];
                        acc[fr >> 2][fr & 3][2] += v[2];
                        acc[fr >> 2][fr & 3][3] += v[3];
                    }
            }
            __syncthreads();
        }
    }

    if (kg != 0) return;
    const int j = ((c0 + wn * 64) >> 6) * 16 + fl;
    #pragma unroll
    for (int mi = 0; mi < MI; ++mi) {
        #pragma unroll
        for (int r = 0; r < 4; ++r) {
            const int m = m0 + wm * MI * 16 + mi * 16 + (lane >> 4) * 4 + r;
            if (m >= n) continue;
            const u16* gx = GXl + (size_t)m * 4096 + c0 + wn * 64 + fl;
            const float i_ = acc[mi][0][r] + h2f(__builtin_nontemporal_load(gx));
            const float f_ = acc[mi][1][r] + h2f(__builtin_nontemporal_load(gx + 16));
            const float g_ = acc[mi][2][r] + h2f(__builtin_nontemporal_load(gx + 32));
            const float o_ = acc[mi][3][r] + h2f(__builtin_nontemporal_load(gx + 48));
            const float cc = __builtin_nontemporal_load(cprev + (size_t)m * 1024 + j);
            const float cn = fsig(f_) * cc + fsig(i_) * ftanh(g_);
            const float hn = fsig(o_) * ftanh(cn);
            if (hnext)
                hnext[(size_t)(m >> 1) * 2048 + (m & 1) * 1024 + j] = f2bf(hn);
            if (!(m & 1))
                __builtin_nontemporal_store(cn, cnext + (size_t)(m >> 1) * 1024 + j);
            if (outp) { outp[j] = hn; outp[1024 + j] = cn; }
        }
    }
}

// ---------------------------------------------------------------- launcher
extern "C" void kernel_launch(void* const* d_in, const int* in_sizes, int n_in,
                              void* d_out, int out_size, void* d_ws, size_t ws_size,
                              hipStream_t stream) {
    const float* emb  = (const float*)d_in[0];
    const float* W_ih = (const float*)d_in[1];
    const float* W_hh = (const float*)d_in[2];
    const float* b_ih = (const float*)d_in[3];
    const float* b_hh = (const float*)d_in[4];
    float* out = (float*)d_out;

    char* p = (char*)d_ws;
    float* bge  = (float*)p;  p += 16384;
    u16* Wih_p  = (u16*)p;    p += (size_t)4096 * 1024 * 2;   //  8.4 MB
    u16* Whh_p  = (u16*)p;    p += (size_t)4096 * 2048 * 2;   // 16.8 MB
    u16* xb     = (u16*)p;    p += (size_t)4096 * 1024 * 2;   //  8.4 MB
    u16* GX     = (u16*)p;    p += (size_t)4096 * 4096 * 2;   // 33.6 MB (rows<2047 used)
    u16* Hcat   = (u16*)p;    p += (size_t)4096 * 2048 * 2;   // 16.8 MB
    float* cbA  = (float*)p;  p += (size_t)1024 * 1024 * 4;   //  4.2 MB
    float* cbB  = (float*)p;  p += (size_t)1024 * 1024 * 4;   //  4.2 MB

    prep<<<16399, 256, 0, stream>>>(W_ih, W_hh, emb, b_ih, b_hh,
                                    Wih_p, Whh_p, xb, bge);

    #define OFF(k) (4096 - (2 << (k)))

    // GX (rows < 2047) + fused level-11 cell (rows >= 2047).
    gemm_gx<<<dim3(32, 32), 256, 0, stream>>>(
        xb, Wih_p, bge, GX, Hcat + (size_t)OFF(10) * 2048, cbA);

    const float* cprev = cbA;
    float* cbufs[2] = {cbB, cbA};
    int t = 0;
    for (int k = TREE_DEPTH - 2; k >= 0; --k) {
        const int n = 1 << k;
        const u16* A = Hcat + (size_t)OFF(k) * 2048;
        const u16* GXl = GX + (size_t)(n - 1) * 4096;
        u16* hnext = (k > 0) ? (Hcat + (size_t)OFF(k - 1) * 2048) : nullptr;
        float* cnext = cbufs[t];
        float* outp = (k == 0) ? out : nullptr;

        if (k == 10) {
            // BM=64, BN=128, KG=2, 256 thr: 512 blocks (2/CU).
            fused_level<4, 1, 2, 2><<<dim3(16, 32), 256, 0, stream>>>(
                A, Whh_p, GXl, cprev, hnext, cnext, outp, n);
        } else if (k == 9) {
            // BM=32, BN=128, KG=2, 256 thr: 512 blocks (2/CU).
            fused_level<2, 1, 2, 2><<<dim3(16, 32), 256, 0, stream>>>(
                A, Whh_p, GXl, cprev, hnext, cnext, outp, n);
        } else if (k == 8) {
            // BM=16, BN=64, KG=4, 256 thr: 1024 blocks (4/CU).
            fused_level<1, 1, 1, 4><<<dim3(16, 64), 256, 0, stream>>>(
                A, Whh_p, GXl, cprev, hnext, cnext, outp, n);
        } else {
            // BM=16, BN=64, KG=8, 512 thr: up to 512 blocks.
            const int gx = (n >= 16) ? n / 16 : 1;
            fused_level<1, 1, 1, 8><<<dim3(gx, 64), 512, 0, stream>>>(
                A, Whh_p, GXl, cprev, hnext, cnext, outp, n);
        }
        cprev = cnext; t ^= 1;
    }
}